// Round 2
// baseline (5319.134 us; speedup 1.0000x reference)
//
#include <hip/hip_runtime.h>
#include <hip/hip_bf16.h>
#include <math.h>

#define NB 8192
#define NS 12
#define NH 8
#define NDK 64
#define NDM 512

typedef __attribute__((ext_vector_type(8))) short bf16x8;
typedef __attribute__((ext_vector_type(4))) float f32x4;

__global__ __launch_bounds__(512) void wcvt_kernel(const float* __restrict__ W,
                                                   __hip_bfloat16* __restrict__ Wb) {
    int i = blockIdx.x * 512 + threadIdx.x;
    Wb[i] = __float2bfloat16(W[i]);
}

__global__ __launch_bounds__(512, 4) void mha_fused2_kernel(
    const float* __restrict__ gq, const float* __restrict__ gk, const float* __restrict__ gv,
    const int* __restrict__ gmask, const float* __restrict__ gcw, const float* __restrict__ gcb,
    const __hip_bfloat16* __restrict__ Wb, const float* __restrict__ gbo,
    float* __restrict__ gout)
{
    // staging: [wave][q/k][16 rows][72 cols] bf16 = 36864 B; overlaid later by abuf [16][520] bf16 (16640 B)
    __shared__ __align__(16) short ovbuf[18432];
    __shared__ __align__(16) float probs[NH][16][16];   // 8192 B
    __shared__ __align__(16) float wt[3][12][12];       // transposed conv weights [tap][in_ch][out_ch]
    __shared__ __align__(16) float bconv[12];
    // total ~46.8 KB -> 2 blocks/CU at <=128 VGPR

    const int b   = blockIdx.x;
    const int tid = threadIdx.x;
    const int wv  = tid >> 6;      // wave == head h
    const int ln  = tid & 63;      // lane == d
    const int h = wv, d = ln;

    if (tid < 432) {
        int t = tid / 144, rem = tid - t * 144;
        int s2 = rem / 12, s = rem - s2 * 12;
        wt[t][s2][s] = gcw[s * 36 + s2 * 3 + t];
    } else if (tid < 444) {
        bconv[tid - 432] = gcb[tid - 432];
    }
    __syncthreads();

    const size_t xoff = (size_t)b * (NS * NDM);

    float vv[12];   // conv(v), kept in registers
    float pv[12];   // attention output rows for this (h, d)

    // ---- conv for q, k (staged to LDS bf16) and v (registers) ----
    for (int t3 = 0; t3 < 3; ++t3) {
        const float* xb = ((t3 == 0) ? gq : (t3 == 1) ? gk : gv) + xoff;
        float ns[12];
        #pragma unroll
        for (int s = 0; s < 12; ++s) {
            float a  = xb[s * 512 + h * 64 + d];
            float am = (h > 0) ? xb[s * 512 + (h - 1) * 64 + d] : 0.f;
            float ap = (h < 7) ? xb[s * 512 + (h + 1) * 64 + d] : 0.f;
            ns[s] = a + am + ap;
        }
        f32x4 o0 = *(const f32x4*)&bconv[0];
        f32x4 o1 = *(const f32x4*)&bconv[4];
        f32x4 o2 = *(const f32x4*)&bconv[8];
        #pragma unroll
        for (int s2 = 0; s2 < 12; ++s2) {
            float n0 = ns[s2];
            float nm = __shfl_up(n0, 1);   if (d == 0)  nm = 0.f;   // zero-pad at d=-1
            float np = __shfl_down(n0, 1); if (d == 63) np = 0.f;   // zero-pad at d=64
            const f32x4* w0 = (const f32x4*)&wt[0][s2][0];
            const f32x4* w1 = (const f32x4*)&wt[1][s2][0];
            const f32x4* w2 = (const f32x4*)&wt[2][s2][0];
            o0 += w0[0] * nm + w1[0] * n0 + w2[0] * np;
            o1 += w0[1] * nm + w1[1] * n0 + w2[1] * np;
            o2 += w0[2] * nm + w1[2] * n0 + w2[2] * np;
        }
        if (t3 < 2) {
            __hip_bfloat16* st = (__hip_bfloat16*)(ovbuf + (wv * 2 + t3) * 1152);
            #pragma unroll
            for (int s = 0; s < 4; ++s) st[s * 72 + d]       = __float2bfloat16(o0[s]);
            #pragma unroll
            for (int s = 0; s < 4; ++s) st[(s + 4) * 72 + d] = __float2bfloat16(o1[s]);
            #pragma unroll
            for (int s = 0; s < 4; ++s) st[(s + 8) * 72 + d] = __float2bfloat16(o2[s]);
        } else {
            #pragma unroll
            for (int s = 0; s < 4; ++s) { vv[s] = o0[s]; vv[s + 4] = o1[s]; vv[s + 8] = o2[s]; }
        }
    }

    // ---- scores via MFMA (wave-local): S = Qc * Kc^T, m=qi, n=kj, k=d ----
    const short* qsp = ovbuf + (wv * 2 + 0) * 1152;
    const short* ksp = ovbuf + (wv * 2 + 1) * 1152;
    const int rA = ln & 15, g = ln >> 4;
    bf16x8 aq0 = *(const bf16x8*)(qsp + rA * 72 + g * 8);
    bf16x8 aq1 = *(const bf16x8*)(qsp + rA * 72 + 32 + g * 8);
    bf16x8 bk0 = *(const bf16x8*)(ksp + rA * 72 + g * 8);
    bf16x8 bk1 = *(const bf16x8*)(ksp + rA * 72 + 32 + g * 8);
    f32x4 sc = {0.f, 0.f, 0.f, 0.f};
    sc = __builtin_amdgcn_mfma_f32_16x16x32_bf16(aq0, bk0, sc, 0, 0, 0);
    sc = __builtin_amdgcn_mfma_f32_16x16x32_bf16(aq1, bk1, sc, 0, 0, 0);

    // ---- mask + softmax (rows live in 16-lane groups; col kj = lane&15) ----
    const int kj = rA;
    const int* mrow = gmask + (size_t)b * 144;
    #pragma unroll
    for (int r = 0; r < 4; ++r) {
        int qi = g * 4 + r;
        float s = sc[r] * 0.125f;
        if (kj >= 12) s = -INFINITY;                       // pad cols excluded
        else if (qi < 12 && mrow[qi * 12 + kj] == 0) s = -1e9f;
        float m = s;
        #pragma unroll
        for (int off = 1; off < 16; off <<= 1) m = fmaxf(m, __shfl_xor(m, off, 16));
        float e = __expf(s - m);
        float sum = e;
        #pragma unroll
        for (int off = 1; off < 16; off <<= 1) sum += __shfl_xor(sum, off, 16);
        probs[wv][qi][kj] = e / sum;
    }

    // ---- PV (wave-local): pv[qi] = sum_kj P[qi][kj] * v[kj][d] ----
    #pragma unroll
    for (int qi = 0; qi < 12; ++qi) {
        const f32x4* pr = (const f32x4*)&probs[wv][qi][0];
        f32x4 p0 = pr[0], p1 = pr[1], p2 = pr[2];
        float acc = 0.f;
        #pragma unroll
        for (int j = 0; j < 4; ++j) acc += p0[j] * vv[j] + p1[j] * vv[j + 4] + p2[j] * vv[j + 8];
        pv[qi] = acc;
    }

    __syncthreads();   // all waves done reading q/k staging; overlay region becomes abuf

    // ---- attention output -> abuf bf16 [16][520] (rows 12..15 zeroed) ----
    __hip_bfloat16* ab = (__hip_bfloat16*)ovbuf;
    #pragma unroll
    for (int qi = 0; qi < 12; ++qi) ab[qi * 520 + h * 64 + d] = __float2bfloat16(pv[qi]);
    {
        unsigned* az = (unsigned*)(ovbuf + 12 * 520);
        for (int i = tid; i < 1040; i += 512) az[i] = 0u;
    }
    __syncthreads();

    // ---- projection: out[m][n] = sum_k A[m][k] * W[n][k] + b[n]  (bf16 MFMA) ----
    {
        const short* Ws = (const short*)Wb;
        const short* As = ovbuf;
        f32x4 acc[4] = {};
        const int n_lane = wv * 64 + rA;
        #pragma unroll 4
        for (int kk = 0; kk < 16; ++kk) {
            int k0 = kk * 32 + g * 8;
            bf16x8 af = *(const bf16x8*)(As + rA * 520 + k0);
            #pragma unroll
            for (int i = 0; i < 4; ++i) {
                bf16x8 bfg = *(const bf16x8*)(Ws + (size_t)(n_lane + i * 16) * NDM + k0);
                acc[i] = __builtin_amdgcn_mfma_f32_16x16x32_bf16(af, bfg, acc[i], 0, 0, 0);
            }
        }
        float* outb = gout + (size_t)b * (NS * NDM);
        const int m0 = g * 4;
        #pragma unroll
        for (int i = 0; i < 4; ++i) {
            int n = wv * 64 + i * 16 + rA;
            float bias = gbo[n];
            #pragma unroll
            for (int r = 0; r < 4; ++r) {
                int m = m0 + r;
                if (m < 12) outb[m * NDM + n] = acc[i][r] + bias;
            }
        }
    }
}

extern "C" void kernel_launch(void* const* d_in, const int* in_sizes, int n_in,
                              void* d_out, int out_size, void* d_ws, size_t ws_size,
                              hipStream_t stream) {
    const float* q    = (const float*)d_in[0];
    const float* k    = (const float*)d_in[1];
    const float* v    = (const float*)d_in[2];
    const int*   mask = (const int*)d_in[3];
    const float* cw   = (const float*)d_in[4];
    const float* cb   = (const float*)d_in[5];
    const float* W    = (const float*)d_in[6];
    const float* bo   = (const float*)d_in[7];
    __hip_bfloat16* Wb = (__hip_bfloat16*)d_ws;   // 512 KB bf16 copy of W_out

    hipLaunchKernelGGL(wcvt_kernel, dim3(512), dim3(512), 0, stream, W, Wb);
    hipLaunchKernelGGL(mha_fused2_kernel, dim3(NB), dim3(512), 0, stream,
                       q, k, v, mask, cw, cb, Wb, bo, (float*)d_out);
}

// Round 3
// 3899.744 us; speedup vs baseline: 1.3640x; 1.3640x over previous
//
#include <hip/hip_runtime.h>
#include <hip/hip_bf16.h>
#include <math.h>

#define NB 8192
#define NS 12
#define NH 8
#define NDK 64
#define NDM 512

typedef __attribute__((ext_vector_type(8))) short bf16x8;
typedef __attribute__((ext_vector_type(4))) float f32x4;

__global__ __launch_bounds__(512) void wcvt_kernel(const float* __restrict__ W,
                                                   __hip_bfloat16* __restrict__ Wb) {
    int i = blockIdx.x * 512 + threadIdx.x;
    Wb[i] = __float2bfloat16(W[i]);
}

__global__ __launch_bounds__(512) void mha_fused3_kernel(
    const float* __restrict__ gq, const float* __restrict__ gk, const float* __restrict__ gv,
    const int* __restrict__ gmask, const float* __restrict__ gcw, const float* __restrict__ gcb,
    const __hip_bfloat16* __restrict__ Wb, const float* __restrict__ gbo,
    float* __restrict__ gout)
{
    // staging: [wave][q/k][16 rows][72 cols] bf16 = 36864 B; overlaid later by abuf [16][520] bf16 (16640 B)
    __shared__ __align__(16) short ovbuf[18432];
    __shared__ __align__(16) float probs[NH][16][16];   // 8192 B
    __shared__ __align__(16) float wt[3][12][12];       // transposed conv weights [tap][in_ch][out_ch]
    __shared__ __align__(16) float bconv[12];
    // total ~46.8 KB

    const int b   = blockIdx.x;
    const int tid = threadIdx.x;
    const int wv  = tid >> 6;      // wave == head h
    const int ln  = tid & 63;      // lane == d
    const int h = wv, d = ln;

    if (tid < 432) {
        int t = tid / 144, rem = tid - t * 144;
        int s2 = rem / 12, s = rem - s2 * 12;
        wt[t][s2][s] = gcw[s * 36 + s2 * 3 + t];
    } else if (tid < 444) {
        bconv[tid - 432] = gcb[tid - 432];
    }
    __syncthreads();

    const size_t xoff = (size_t)b * (NS * NDM);

    float vv[12];   // conv(v), kept in registers
    float pv[12];   // attention output rows for this (h, d)

    // ---- conv for q, k (staged to LDS bf16) and v (registers) ----
    for (int t3 = 0; t3 < 3; ++t3) {
        const float* xb = ((t3 == 0) ? gq : (t3 == 1) ? gk : gv) + xoff;
        f32x4 o0 = *(const f32x4*)&bconv[0];
        f32x4 o1 = *(const f32x4*)&bconv[4];
        f32x4 o2 = *(const f32x4*)&bconv[8];
        #pragma unroll
        for (int s2 = 0; s2 < 12; ++s2) {
            // neighbor sum over head axis, computed on the fly (no ns[] array)
            float a  = xb[s2 * 512 + h * 64 + d];
            float am = (h > 0) ? xb[s2 * 512 + (h - 1) * 64 + d] : 0.f;
            float ap = (h < 7) ? xb[s2 * 512 + (h + 1) * 64 + d] : 0.f;
            float n0 = a + am + ap;
            float nm = __shfl_up(n0, 1);   if (d == 0)  nm = 0.f;   // zero-pad at d=-1
            float np = __shfl_down(n0, 1); if (d == 63) np = 0.f;   // zero-pad at d=64
            const f32x4* w0 = (const f32x4*)&wt[0][s2][0];
            const f32x4* w1 = (const f32x4*)&wt[1][s2][0];
            const f32x4* w2 = (const f32x4*)&wt[2][s2][0];
            o0 += w0[0] * nm + w1[0] * n0 + w2[0] * np;
            o1 += w0[1] * nm + w1[1] * n0 + w2[1] * np;
            o2 += w0[2] * nm + w1[2] * n0 + w2[2] * np;
        }
        if (t3 < 2) {
            __hip_bfloat16* st = (__hip_bfloat16*)(ovbuf + (wv * 2 + t3) * 1152);
            #pragma unroll
            for (int s = 0; s < 4; ++s) st[s * 72 + d]       = __float2bfloat16(o0[s]);
            #pragma unroll
            for (int s = 0; s < 4; ++s) st[(s + 4) * 72 + d] = __float2bfloat16(o1[s]);
            #pragma unroll
            for (int s = 0; s < 4; ++s) st[(s + 8) * 72 + d] = __float2bfloat16(o2[s]);
        } else {
            #pragma unroll
            for (int s = 0; s < 4; ++s) { vv[s] = o0[s]; vv[s + 4] = o1[s]; vv[s + 8] = o2[s]; }
        }
    }

    // ---- scores via MFMA (wave-local): S = Qc * Kc^T, m=qi, n=kj, k=d ----
    const short* qsp = ovbuf + (wv * 2 + 0) * 1152;
    const short* ksp = ovbuf + (wv * 2 + 1) * 1152;
    const int rA = ln & 15, g = ln >> 4;
    bf16x8 aq0 = *(const bf16x8*)(qsp + rA * 72 + g * 8);
    bf16x8 aq1 = *(const bf16x8*)(qsp + rA * 72 + 32 + g * 8);
    bf16x8 bk0 = *(const bf16x8*)(ksp + rA * 72 + g * 8);
    bf16x8 bk1 = *(const bf16x8*)(ksp + rA * 72 + 32 + g * 8);
    f32x4 sc = {0.f, 0.f, 0.f, 0.f};
    sc = __builtin_amdgcn_mfma_f32_16x16x32_bf16(aq0, bk0, sc, 0, 0, 0);
    sc = __builtin_amdgcn_mfma_f32_16x16x32_bf16(aq1, bk1, sc, 0, 0, 0);

    // ---- mask + softmax (rows live in 16-lane groups; col kj = lane&15) ----
    const int kj = rA;
    const int* mrow = gmask + (size_t)b * 144;
    #pragma unroll
    for (int r = 0; r < 4; ++r) {
        int qi = g * 4 + r;
        float s = sc[r] * 0.125f;
        if (kj >= 12) s = -INFINITY;                       // pad cols excluded
        else if (qi < 12 && mrow[qi * 12 + kj] == 0) s = -1e9f;
        float m = s;
        #pragma unroll
        for (int off = 1; off < 16; off <<= 1) m = fmaxf(m, __shfl_xor(m, off, 16));
        float e = __expf(s - m);
        float sum = e;
        #pragma unroll
        for (int off = 1; off < 16; off <<= 1) sum += __shfl_xor(sum, off, 16);
        probs[wv][qi][kj] = e / sum;
    }

    // ---- PV (wave-local): pv[qi] = sum_kj P[qi][kj] * v[kj][d] ----
    #pragma unroll
    for (int qi = 0; qi < 12; ++qi) {
        const f32x4* pr = (const f32x4*)&probs[wv][qi][0];
        f32x4 p0 = pr[0], p1 = pr[1], p2 = pr[2];
        float acc = 0.f;
        #pragma unroll
        for (int j = 0; j < 4; ++j) acc += p0[j] * vv[j] + p1[j] * vv[j + 4] + p2[j] * vv[j + 8];
        pv[qi] = acc;
    }

    __syncthreads();   // all waves done reading q/k staging; overlay region becomes abuf

    // ---- attention output -> abuf bf16 [16][520] (rows 12..15 zeroed) ----
    __hip_bfloat16* ab = (__hip_bfloat16*)ovbuf;
    #pragma unroll
    for (int qi = 0; qi < 12; ++qi) ab[qi * 520 + h * 64 + d] = __float2bfloat16(pv[qi]);
    {
        unsigned* az = (unsigned*)(ovbuf + 12 * 520);
        for (int i = tid; i < 1040; i += 512) az[i] = 0u;
    }
    __syncthreads();

    // ---- projection: out[m][n] = sum_k A[m][k] * W[n][k] + b[n]  (bf16 MFMA) ----
    {
        const short* Ws = (const short*)Wb;
        const short* As = ovbuf;
        f32x4 acc[4] = {};
        const int n_lane = wv * 64 + rA;
        #pragma unroll 4
        for (int kk = 0; kk < 16; ++kk) {
            int k0 = kk * 32 + g * 8;
            bf16x8 af = *(const bf16x8*)(As + rA * 520 + k0);
            #pragma unroll
            for (int i = 0; i < 4; ++i) {
                bf16x8 bfg = *(const bf16x8*)(Ws + (size_t)(n_lane + i * 16) * NDM + k0);
                acc[i] = __builtin_amdgcn_mfma_f32_16x16x32_bf16(af, bfg, acc[i], 0, 0, 0);
            }
        }
        float* outb = gout + (size_t)b * (NS * NDM);
        const int m0 = g * 4;
        #pragma unroll
        for (int i = 0; i < 4; ++i) {
            int n = wv * 64 + i * 16 + rA;
            float bias = gbo[n];
            #pragma unroll
            for (int r = 0; r < 4; ++r) {
                int m = m0 + r;
                if (m < 12) outb[m * NDM + n] = acc[i][r] + bias;
            }
        }
    }
}

extern "C" void kernel_launch(void* const* d_in, const int* in_sizes, int n_in,
                              void* d_out, int out_size, void* d_ws, size_t ws_size,
                              hipStream_t stream) {
    const float* q    = (const float*)d_in[0];
    const float* k    = (const float*)d_in[1];
    const float* v    = (const float*)d_in[2];
    const int*   mask = (const int*)d_in[3];
    const float* cw   = (const float*)d_in[4];
    const float* cb   = (const float*)d_in[5];
    const float* W    = (const float*)d_in[6];
    const float* bo   = (const float*)d_in[7];
    __hip_bfloat16* Wb = (__hip_bfloat16*)d_ws;   // 512 KB bf16 copy of W_out

    hipLaunchKernelGGL(wcvt_kernel, dim3(512), dim3(512), 0, stream, W, Wb);
    hipLaunchKernelGGL(mha_fused3_kernel, dim3(NB), dim3(512), 0, stream,
                       q, k, v, mask, cw, cb, Wb, bo, (float*)d_out);
}

// Round 4
// 1043.878 us; speedup vs baseline: 5.0956x; 3.7358x over previous
//
#include <hip/hip_runtime.h>
#include <hip/hip_bf16.h>
#include <math.h>

#define NB 8192
#define NS 12
#define NH 8
#define NDK 64
#define NDM 512

typedef __attribute__((ext_vector_type(8))) short bf16x8;
typedef __attribute__((ext_vector_type(4))) float f32x4;

__global__ __launch_bounds__(512) void wcvt_kernel(const float* __restrict__ W,
                                                   __hip_bfloat16* __restrict__ Wb) {
    int i = blockIdx.x * 512 + threadIdx.x;
    Wb[i] = __float2bfloat16(W[i]);
}

__global__ __launch_bounds__(512) void mha_fused4_kernel(
    const float* __restrict__ gq, const float* __restrict__ gk, const float* __restrict__ gv,
    const int* __restrict__ gmask, const float* __restrict__ gcw, const float* __restrict__ gcb,
    const __hip_bfloat16* __restrict__ Wb, const float* __restrict__ gbo,
    float* __restrict__ gout)
{
    __shared__ __align__(16) float xstage[NS][NDM];     // 24576 B: raw input tile, reused q->k->v
    __shared__ __align__(16) short ovbuf[18432];        // 36864 B: q/k bf16 staging [wave][2][16][72]; overlaid by abuf [16][520]
    __shared__ __align__(16) float probs[NH][16][16];   // 8192 B
    __shared__ __align__(16) float wt[3][12][12];       // conv weights [tap][in_ch][out_ch]
    __shared__ __align__(16) float bconv[12];
    // total ~71.4 KB -> 2 blocks/CU

    const int b   = blockIdx.x;
    const int tid = threadIdx.x;
    const int wv  = tid >> 6;      // wave == head h
    const int ln  = tid & 63;      // lane == d
    const int h = wv, d = ln;

    if (tid < 432) {
        int t = tid / 144, rem = tid - t * 144;
        int s2 = rem / 12, s = rem - s2 * 12;
        wt[t][s2][s] = gcw[s * 36 + s2 * 3 + t];
    } else if (tid < 444) {
        bconv[tid - 432] = gcb[tid - 432];
    }

    const size_t xoff = (size_t)b * (NS * NDM);
    float vv[12];   // conv(v), registers (only persistent per-thread array)

    for (int t3 = 0; t3 < 3; ++t3) {
        const float* xb = ((t3 == 0) ? gq : (t3 == 1) ? gk : gv) + xoff;
        {   // cooperative stage: 3 float4 per thread, fully coalesced
            const float4* s4 = (const float4*)xb;
            float4* dst4 = (float4*)&xstage[0][0];
            #pragma unroll
            for (int i = 0; i < 3; ++i) dst4[tid + i * 512] = s4[tid + i * 512];
        }
        __syncthreads();   // xstage ready (also covers wt/bconv on first iter)

        f32x4 o0 = *(const f32x4*)&bconv[0];
        f32x4 o1 = *(const f32x4*)&bconv[4];
        f32x4 o2 = *(const f32x4*)&bconv[8];
        #pragma unroll 4
        for (int s2 = 0; s2 < 12; ++s2) {
            float c  = xstage[s2][h * 64 + d];
            float cm = (h > 0) ? xstage[s2][(h - 1) * 64 + d] : 0.f;
            float cp = (h < 7) ? xstage[s2][(h + 1) * 64 + d] : 0.f;
            float n0 = c + cm + cp;
            float nm = __shfl_up(n0, 1);   if (d == 0)  nm = 0.f;   // zero-pad d=-1
            float np = __shfl_down(n0, 1); if (d == 63) np = 0.f;   // zero-pad d=64
            const f32x4* w0 = (const f32x4*)&wt[0][s2][0];
            const f32x4* w1 = (const f32x4*)&wt[1][s2][0];
            const f32x4* w2 = (const f32x4*)&wt[2][s2][0];
            o0 += w0[0] * nm + w1[0] * n0 + w2[0] * np;
            o1 += w0[1] * nm + w1[1] * n0 + w2[1] * np;
            o2 += w0[2] * nm + w1[2] * n0 + w2[2] * np;
        }
        if (t3 < 2) {
            __hip_bfloat16* st = (__hip_bfloat16*)(ovbuf + (wv * 2 + t3) * 1152);
            #pragma unroll
            for (int s = 0; s < 4; ++s) st[s * 72 + d]       = __float2bfloat16(o0[s]);
            #pragma unroll
            for (int s = 0; s < 4; ++s) st[(s + 4) * 72 + d] = __float2bfloat16(o1[s]);
            #pragma unroll
            for (int s = 0; s < 4; ++s) st[(s + 8) * 72 + d] = __float2bfloat16(o2[s]);
            __syncthreads();   // all conv reads of xstage done before next tensor overwrites it
        } else {
            #pragma unroll
            for (int s = 0; s < 4; ++s) { vv[s] = o0[s]; vv[s + 4] = o1[s]; vv[s + 8] = o2[s]; }
        }
    }

    // ---- scores via MFMA (wave-local; staging written by this wave) ----
    const short* qsp = ovbuf + (wv * 2 + 0) * 1152;
    const short* ksp = ovbuf + (wv * 2 + 1) * 1152;
    const int rA = ln & 15, g = ln >> 4;
    bf16x8 aq0 = *(const bf16x8*)(qsp + rA * 72 + g * 8);
    bf16x8 aq1 = *(const bf16x8*)(qsp + rA * 72 + 32 + g * 8);
    bf16x8 bk0 = *(const bf16x8*)(ksp + rA * 72 + g * 8);
    bf16x8 bk1 = *(const bf16x8*)(ksp + rA * 72 + 32 + g * 8);
    f32x4 sc = {0.f, 0.f, 0.f, 0.f};
    sc = __builtin_amdgcn_mfma_f32_16x16x32_bf16(aq0, bk0, sc, 0, 0, 0);
    sc = __builtin_amdgcn_mfma_f32_16x16x32_bf16(aq1, bk1, sc, 0, 0, 0);

    // ---- mask + softmax (row qi in 16-lane groups; col kj = lane&15) ----
    const int kj = rA;
    const int* mrow = gmask + (size_t)b * 144;
    #pragma unroll
    for (int r = 0; r < 4; ++r) {
        int qi = g * 4 + r;
        float s = sc[r] * 0.125f;
        if (kj >= 12) s = -INFINITY;
        else if (qi < 12 && mrow[qi * 12 + kj] == 0) s = -1e9f;
        float m = s;
        #pragma unroll
        for (int off = 1; off < 16; off <<= 1) m = fmaxf(m, __shfl_xor(m, off, 16));
        float e = __expf(s - m);
        float sum = e;
        #pragma unroll
        for (int off = 1; off < 16; off <<= 1) sum += __shfl_xor(sum, off, 16);
        probs[wv][qi][kj] = e / sum;
    }

    __syncthreads();   // all waves' q/k frag loads complete; ovbuf becomes abuf

    // ---- PV: compute each row and write straight to abuf (no pv[] array) ----
    __hip_bfloat16* ab = (__hip_bfloat16*)ovbuf;
    #pragma unroll
    for (int qi = 0; qi < 12; ++qi) {
        const f32x4* pr = (const f32x4*)&probs[wv][qi][0];   // broadcast reads
        f32x4 p0 = pr[0], p1 = pr[1], p2 = pr[2];
        float acc = 0.f;
        #pragma unroll
        for (int j = 0; j < 4; ++j) acc += p0[j] * vv[j] + p1[j] * vv[j + 4] + p2[j] * vv[j + 8];
        ab[qi * 520 + h * 64 + d] = __float2bfloat16(acc);
    }
    {
        unsigned* az = (unsigned*)(ovbuf + 12 * 520);
        for (int i = tid; i < 1040; i += 512) az[i] = 0u;   // zero rows 12..15
    }
    __syncthreads();

    // ---- projection: out[m][n] = sum_k A[m][k] * W[n][k] + b[n]  (bf16 MFMA) ----
    {
        const short* Ws = (const short*)Wb;
        const short* As = ovbuf;
        f32x4 acc[4] = {};
        const int n_lane = wv * 64 + rA;
        #pragma unroll 4
        for (int kk = 0; kk < 16; ++kk) {
            int k0 = kk * 32 + g * 8;
            bf16x8 af = *(const bf16x8*)(As + rA * 520 + k0);
            #pragma unroll
            for (int i = 0; i < 4; ++i) {
                bf16x8 bfg = *(const bf16x8*)(Ws + (size_t)(n_lane + i * 16) * NDM + k0);
                acc[i] = __builtin_amdgcn_mfma_f32_16x16x32_bf16(af, bfg, acc[i], 0, 0, 0);
            }
        }
        float* outb = gout + (size_t)b * (NS * NDM);
        const int m0 = g * 4;
        #pragma unroll
        for (int i = 0; i < 4; ++i) {
            int n = wv * 64 + i * 16 + rA;
            float bias = gbo[n];
            #pragma unroll
            for (int r = 0; r < 4; ++r) {
                int m = m0 + r;
                if (m < 12) outb[m * NDM + n] = acc[i][r] + bias;
            }
        }
    }
}

extern "C" void kernel_launch(void* const* d_in, const int* in_sizes, int n_in,
                              void* d_out, int out_size, void* d_ws, size_t ws_size,
                              hipStream_t stream) {
    const float* q    = (const float*)d_in[0];
    const float* k    = (const float*)d_in[1];
    const float* v    = (const float*)d_in[2];
    const int*   mask = (const int*)d_in[3];
    const float* cw   = (const float*)d_in[4];
    const float* cb   = (const float*)d_in[5];
    const float* W    = (const float*)d_in[6];
    const float* bo   = (const float*)d_in[7];
    __hip_bfloat16* Wb = (__hip_bfloat16*)d_ws;   // 512 KB bf16 copy of W_out

    hipLaunchKernelGGL(wcvt_kernel, dim3(512), dim3(512), 0, stream, W, Wb);
    hipLaunchKernelGGL(mha_fused4_kernel, dim3(NB), dim3(512), 0, stream,
                       q, k, v, mask, cw, cb, Wb, bo, (float*)d_out);
}

// Round 5
// 934.616 us; speedup vs baseline: 5.6913x; 1.1169x over previous
//
#include <hip/hip_runtime.h>
#include <hip/hip_bf16.h>
#include <math.h>

#define NB 8192
#define NS 12
#define NH 8
#define NDK 64
#define NDM 512

typedef __attribute__((ext_vector_type(8))) short bf16x8;
typedef __attribute__((ext_vector_type(4))) float f32x4;

static __device__ __forceinline__ short f2bfb(float x) {
    __hip_bfloat16 h = __float2bfloat16(x);
    return *(short*)&h;
}
static __device__ __forceinline__ float bfb2f(short s) {
    unsigned u = ((unsigned)(unsigned short)s) << 16;
    return __uint_as_float(u);
}

__global__ __launch_bounds__(512) void wcvt_kernel(const float* __restrict__ W,
                                                   __hip_bfloat16* __restrict__ Wb) {
    int i = blockIdx.x * 512 + threadIdx.x;
    Wb[i] = __float2bfloat16(W[i]);
}

// ---------------- Kernel A: conv for one (batch, tensor) ----------------
// qc/kc layout: [B][H][12][64] bf16 ; vc layout: [B][H][64][12] bf16
__global__ __launch_bounds__(512) void conv_kernel(
    const float* __restrict__ gq, const float* __restrict__ gk, const float* __restrict__ gv,
    const float* __restrict__ gcw, const float* __restrict__ gcb,
    short* __restrict__ qc, short* __restrict__ kc, short* __restrict__ vc)
{
    __shared__ __align__(16) float xstage[NS][NDM];   // 24576 B
    __shared__ __align__(16) float wt[3][12][12];
    __shared__ __align__(16) float bconv[12];
    // ~26.4 KB -> 4 blocks/CU (wave-capped)

    const int b   = blockIdx.x;
    const int t3  = blockIdx.y;          // 0=q, 1=k, 2=v
    const int tid = threadIdx.x;
    const int h   = tid >> 6;
    const int d   = tid & 63;

    if (tid < 432) {
        int t = tid / 144, rem = tid - t * 144;
        int s2 = rem / 12, s = rem - s2 * 12;
        wt[t][s2][s] = gcw[s * 36 + s2 * 3 + t];
    } else if (tid < 444) {
        bconv[tid - 432] = gcb[tid - 432];
    }

    const float* xb = ((t3 == 0) ? gq : (t3 == 1) ? gk : gv) + (size_t)b * (NS * NDM);
    {
        const float4* s4 = (const float4*)xb;
        float4* dst4 = (float4*)&xstage[0][0];
        #pragma unroll
        for (int i = 0; i < 3; ++i) dst4[tid + i * 512] = s4[tid + i * 512];
    }
    __syncthreads();

    f32x4 o0 = *(const f32x4*)&bconv[0];
    f32x4 o1 = *(const f32x4*)&bconv[4];
    f32x4 o2 = *(const f32x4*)&bconv[8];
    #pragma unroll 4
    for (int s2 = 0; s2 < 12; ++s2) {
        float c  = xstage[s2][h * 64 + d];
        float cm = (h > 0) ? xstage[s2][(h - 1) * 64 + d] : 0.f;
        float cp = (h < 7) ? xstage[s2][(h + 1) * 64 + d] : 0.f;
        float n0 = c + cm + cp;
        float nm = __shfl_up(n0, 1);   if (d == 0)  nm = 0.f;
        float np = __shfl_down(n0, 1); if (d == 63) np = 0.f;
        const f32x4* w0 = (const f32x4*)&wt[0][s2][0];
        const f32x4* w1 = (const f32x4*)&wt[1][s2][0];
        const f32x4* w2 = (const f32x4*)&wt[2][s2][0];
        o0 += w0[0] * nm + w1[0] * n0 + w2[0] * np;
        o1 += w0[1] * nm + w1[1] * n0 + w2[1] * np;
        o2 += w0[2] * nm + w1[2] * n0 + w2[2] * np;
    }

    if (t3 < 2) {
        short* dst = ((t3 == 0) ? qc : kc) + ((size_t)b * NH + h) * (NS * NDK);
        #pragma unroll
        for (int s = 0; s < 4; ++s) dst[s * 64 + d]       = f2bfb(o0[s]);
        #pragma unroll
        for (int s = 0; s < 4; ++s) dst[(s + 4) * 64 + d] = f2bfb(o1[s]);
        #pragma unroll
        for (int s = 0; s < 4; ++s) dst[(s + 8) * 64 + d] = f2bfb(o2[s]);
    } else {
        short* dst = vc + (((size_t)b * NH + h) * NDK + d) * NS;   // 12 contiguous bf16
        short4 p0, p1, p2;
        p0.x = f2bfb(o0[0]); p0.y = f2bfb(o0[1]); p0.z = f2bfb(o0[2]); p0.w = f2bfb(o0[3]);
        p1.x = f2bfb(o1[0]); p1.y = f2bfb(o1[1]); p1.z = f2bfb(o1[2]); p1.w = f2bfb(o1[3]);
        p2.x = f2bfb(o2[0]); p2.y = f2bfb(o2[1]); p2.z = f2bfb(o2[2]); p2.w = f2bfb(o2[3]);
        short4* d4 = (short4*)dst;
        d4[0] = p0; d4[1] = p1; d4[2] = p2;
    }
}

// ---------------- Kernel B: attention + projection for one batch ----------------
__global__ __launch_bounds__(512) void attn_kernel(
    const short* __restrict__ qc, const short* __restrict__ kc, const short* __restrict__ vc,
    const int* __restrict__ gmask, const __hip_bfloat16* __restrict__ Wb,
    const float* __restrict__ gbo, float* __restrict__ gout)
{
    __shared__ __align__(16) float probs[NH][16][16];   // 8192 B
    __shared__ __align__(16) short abuf[16 * 520];      // 16640 B
    // ~25 KB

    const int b   = blockIdx.x;
    const int tid = threadIdx.x;
    const int wv  = tid >> 6;      // wave == head
    const int ln  = tid & 63;
    const int h = wv, d = ln;
    const int rA = ln & 15, g = ln >> 4;

    // ---- q/k MFMA fragments straight from global (bf16) ----
    const short* qs = qc + ((size_t)b * NH + h) * (NS * NDK);
    const short* ks = kc + ((size_t)b * NH + h) * (NS * NDK);
    bf16x8 aq0 = *(const bf16x8*)(qs + rA * 64 + g * 8);
    bf16x8 aq1 = *(const bf16x8*)(qs + rA * 64 + 32 + g * 8);
    bf16x8 bk0 = *(const bf16x8*)(ks + rA * 64 + g * 8);
    bf16x8 bk1 = *(const bf16x8*)(ks + rA * 64 + 32 + g * 8);
    f32x4 sc = {0.f, 0.f, 0.f, 0.f};
    sc = __builtin_amdgcn_mfma_f32_16x16x32_bf16(aq0, bk0, sc, 0, 0, 0);
    sc = __builtin_amdgcn_mfma_f32_16x16x32_bf16(aq1, bk1, sc, 0, 0, 0);

    // ---- v for this (h, d): 12 contiguous bf16 ----
    float vv[12];
    {
        const short4* vp = (const short4*)(vc + (((size_t)b * NH + h) * NDK + d) * NS);
        short4 v0 = vp[0], v1 = vp[1], v2 = vp[2];
        vv[0] = bfb2f(v0.x); vv[1] = bfb2f(v0.y); vv[2]  = bfb2f(v0.z); vv[3]  = bfb2f(v0.w);
        vv[4] = bfb2f(v1.x); vv[5] = bfb2f(v1.y); vv[6]  = bfb2f(v1.z); vv[7]  = bfb2f(v1.w);
        vv[8] = bfb2f(v2.x); vv[9] = bfb2f(v2.y); vv[10] = bfb2f(v2.z); vv[11] = bfb2f(v2.w);
    }

    // ---- mask + softmax (row qi in 16-lane groups; col kj = lane&15) ----
    const int kj = rA;
    const int* mrow = gmask + (size_t)b * 144;
    #pragma unroll
    for (int r = 0; r < 4; ++r) {
        int qi = g * 4 + r;
        float s = sc[r] * 0.125f;
        if (kj >= 12) s = -INFINITY;
        else if (qi < 12 && mrow[qi * 12 + kj] == 0) s = -1e9f;
        float m = s;
        #pragma unroll
        for (int off = 1; off < 16; off <<= 1) m = fmaxf(m, __shfl_xor(m, off, 16));
        float e = __expf(s - m);
        float sum = e;
        #pragma unroll
        for (int off = 1; off < 16; off <<= 1) sum += __shfl_xor(sum, off, 16);
        probs[wv][qi][kj] = e / sum;
    }

    // ---- PV -> abuf rows (own wave's probs; no cross-wave dependency yet) ----
    #pragma unroll
    for (int qi = 0; qi < 12; ++qi) {
        const f32x4* pr = (const f32x4*)&probs[wv][qi][0];
        f32x4 p0 = pr[0], p1 = pr[1], p2 = pr[2];
        float acc = 0.f;
        #pragma unroll
        for (int j = 0; j < 4; ++j) acc += p0[j] * vv[j] + p1[j] * vv[j + 4] + p2[j] * vv[j + 8];
        abuf[qi * 520 + h * 64 + d] = f2bfb(acc);
    }
    {
        unsigned* az = (unsigned*)(abuf + 12 * 520);
        for (int i = tid; i < 1040; i += 512) az[i] = 0u;   // zero rows 12..15
    }
    __syncthreads();

    // ---- projection: out[m][n] = sum_k A[m][k] * W[n][k] + b[n] ----
    {
        const short* Ws = (const short*)Wb;
        f32x4 acc[4] = {};
        const int n_lane = wv * 64 + rA;
        #pragma unroll 4
        for (int kk = 0; kk < 16; ++kk) {
            int k0 = kk * 32 + g * 8;
            bf16x8 af = *(const bf16x8*)(abuf + rA * 520 + k0);
            #pragma unroll
            for (int i = 0; i < 4; ++i) {
                bf16x8 bfg = *(const bf16x8*)(Ws + (size_t)(n_lane + i * 16) * NDM + k0);
                acc[i] = __builtin_amdgcn_mfma_f32_16x16x32_bf16(af, bfg, acc[i], 0, 0, 0);
            }
        }
        float* outb = gout + (size_t)b * (NS * NDM);
        const int m0 = g * 4;
        #pragma unroll
        for (int i = 0; i < 4; ++i) {
            int n = wv * 64 + i * 16 + rA;
            float bias = gbo[n];
            #pragma unroll
            for (int r = 0; r < 4; ++r) {
                int m = m0 + r;
                if (m < 12) outb[m * NDM + n] = acc[i][r] + bias;
            }
        }
    }
}

// ---------------- Fallback: round-4 fused kernel (used if ws too small) ----------------
__global__ __launch_bounds__(512) void mha_fused4_kernel(
    const float* __restrict__ gq, const float* __restrict__ gk, const float* __restrict__ gv,
    const int* __restrict__ gmask, const float* __restrict__ gcw, const float* __restrict__ gcb,
    const __hip_bfloat16* __restrict__ Wb, const float* __restrict__ gbo,
    float* __restrict__ gout)
{
    __shared__ __align__(16) float xstage[NS][NDM];
    __shared__ __align__(16) short ovbuf[18432];
    __shared__ __align__(16) float probs[NH][16][16];
    __shared__ __align__(16) float wt[3][12][12];
    __shared__ __align__(16) float bconv[12];

    const int b   = blockIdx.x;
    const int tid = threadIdx.x;
    const int wv  = tid >> 6;
    const int ln  = tid & 63;
    const int h = wv, d = ln;

    if (tid < 432) {
        int t = tid / 144, rem = tid - t * 144;
        int s2 = rem / 12, s = rem - s2 * 12;
        wt[t][s2][s] = gcw[s * 36 + s2 * 3 + t];
    } else if (tid < 444) {
        bconv[tid - 432] = gcb[tid - 432];
    }

    const size_t xoff = (size_t)b * (NS * NDM);
    float vv[12];

    for (int t3 = 0; t3 < 3; ++t3) {
        const float* xb = ((t3 == 0) ? gq : (t3 == 1) ? gk : gv) + xoff;
        {
            const float4* s4 = (const float4*)xb;
            float4* dst4 = (float4*)&xstage[0][0];
            #pragma unroll
            for (int i = 0; i < 3; ++i) dst4[tid + i * 512] = s4[tid + i * 512];
        }
        __syncthreads();

        f32x4 o0 = *(const f32x4*)&bconv[0];
        f32x4 o1 = *(const f32x4*)&bconv[4];
        f32x4 o2 = *(const f32x4*)&bconv[8];
        #pragma unroll 4
        for (int s2 = 0; s2 < 12; ++s2) {
            float c  = xstage[s2][h * 64 + d];
            float cm = (h > 0) ? xstage[s2][(h - 1) * 64 + d] : 0.f;
            float cp = (h < 7) ? xstage[s2][(h + 1) * 64 + d] : 0.f;
            float n0 = c + cm + cp;
            float nm = __shfl_up(n0, 1);   if (d == 0)  nm = 0.f;
            float np = __shfl_down(n0, 1); if (d == 63) np = 0.f;
            const f32x4* w0 = (const f32x4*)&wt[0][s2][0];
            const f32x4* w1 = (const f32x4*)&wt[1][s2][0];
            const f32x4* w2 = (const f32x4*)&wt[2][s2][0];
            o0 += w0[0] * nm + w1[0] * n0 + w2[0] * np;
            o1 += w0[1] * nm + w1[1] * n0 + w2[1] * np;
            o2 += w0[2] * nm + w1[2] * n0 + w2[2] * np;
        }
        if (t3 < 2) {
            __hip_bfloat16* st = (__hip_bfloat16*)(ovbuf + (wv * 2 + t3) * 1152);
            #pragma unroll
            for (int s = 0; s < 4; ++s) st[s * 72 + d]       = __float2bfloat16(o0[s]);
            #pragma unroll
            for (int s = 0; s < 4; ++s) st[(s + 4) * 72 + d] = __float2bfloat16(o1[s]);
            #pragma unroll
            for (int s = 0; s < 4; ++s) st[(s + 8) * 72 + d] = __float2bfloat16(o2[s]);
            __syncthreads();
        } else {
            #pragma unroll
            for (int s = 0; s < 4; ++s) { vv[s] = o0[s]; vv[s + 4] = o1[s]; vv[s + 8] = o2[s]; }
        }
    }

    const short* qsp = ovbuf + (wv * 2 + 0) * 1152;
    const short* ksp = ovbuf + (wv * 2 + 1) * 1152;
    const int rA = ln & 15, g = ln >> 4;
    bf16x8 aq0 = *(const bf16x8*)(qsp + rA * 72 + g * 8);
    bf16x8 aq1 = *(const bf16x8*)(qsp + rA * 72 + 32 + g * 8);
    bf16x8 bk0 = *(const bf16x8*)(ksp + rA * 72 + g * 8);
    bf16x8 bk1 = *(const bf16x8*)(ksp + rA * 72 + 32 + g * 8);
    f32x4 sc = {0.f, 0.f, 0.f, 0.f};
    sc = __builtin_amdgcn_mfma_f32_16x16x32_bf16(aq0, bk0, sc, 0, 0, 0);
    sc = __builtin_amdgcn_mfma_f32_16x16x32_bf16(aq1, bk1, sc, 0, 0, 0);

    const int kj = rA;
    const int* mrow = gmask + (size_t)b * 144;
    #pragma unroll
    for (int r = 0; r < 4; ++r) {
        int qi = g * 4 + r;
        float s = sc[r] * 0.125f;
        if (kj >= 12) s = -INFINITY;
        else if (qi < 12 && mrow[qi * 12 + kj] == 0) s = -1e9f;
        float m = s;
        #pragma unroll
        for (int off = 1; off < 16; off <<= 1) m = fmaxf(m, __shfl_xor(m, off, 16));
        float e = __expf(s - m);
        float sum = e;
        #pragma unroll
        for (int off = 1; off < 16; off <<= 1) sum += __shfl_xor(sum, off, 16);
        probs[wv][qi][kj] = e / sum;
    }

    __syncthreads();

    __hip_bfloat16* ab = (__hip_bfloat16*)ovbuf;
    #pragma unroll
    for (int qi = 0; qi < 12; ++qi) {
        const f32x4* pr = (const f32x4*)&probs[wv][qi][0];
        f32x4 p0 = pr[0], p1 = pr[1], p2 = pr[2];
        float acc = 0.f;
        #pragma unroll
        for (int j = 0; j < 4; ++j) acc += p0[j] * vv[j] + p1[j] * vv[j + 4] + p2[j] * vv[j + 8];
        ab[qi * 520 + h * 64 + d] = __float2bfloat16(acc);
    }
    {
        unsigned* az = (unsigned*)(ovbuf + 12 * 520);
        for (int i = tid; i < 1040; i += 512) az[i] = 0u;
    }
    __syncthreads();

    {
        const short* Ws = (const short*)Wb;
        const short* As = ovbuf;
        f32x4 acc[4] = {};
        const int n_lane = wv * 64 + rA;
        #pragma unroll 4
        for (int kk = 0; kk < 16; ++kk) {
            int k0 = kk * 32 + g * 8;
            bf16x8 af = *(const bf16x8*)(As + rA * 520 + k0);
            #pragma unroll
            for (int i = 0; i < 4; ++i) {
                bf16x8 bfg = *(const bf16x8*)(Ws + (size_t)(n_lane + i * 16) * NDM + k0);
                acc[i] = __builtin_amdgcn_mfma_f32_16x16x32_bf16(af, bfg, acc[i], 0, 0, 0);
            }
        }
        float* outb = gout + (size_t)b * (NS * NDM);
        const int m0 = g * 4;
        #pragma unroll
        for (int i = 0; i < 4; ++i) {
            int n = wv * 64 + i * 16 + rA;
            float bias = gbo[n];
            #pragma unroll
            for (int r = 0; r < 4; ++r) {
                int m = m0 + r;
                if (m < 12) outb[m * NDM + n] = acc[i][r] + bias;
            }
        }
    }
}

extern "C" void kernel_launch(void* const* d_in, const int* in_sizes, int n_in,
                              void* d_out, int out_size, void* d_ws, size_t ws_size,
                              hipStream_t stream) {
    const float* q    = (const float*)d_in[0];
    const float* k    = (const float*)d_in[1];
    const float* v    = (const float*)d_in[2];
    const int*   mask = (const int*)d_in[3];
    const float* cw   = (const float*)d_in[4];
    const float* cb   = (const float*)d_in[5];
    const float* W    = (const float*)d_in[6];
    const float* bo   = (const float*)d_in[7];

    const size_t TEN = (size_t)NB * NH * NS * NDK * sizeof(short);  // 100,663,296 B per tensor
    const size_t REQ = 3 * TEN + (size_t)NDM * NDM * sizeof(short); // + 512 KB for Wb

    if (ws_size >= REQ) {
        short* vc = (short*)d_ws;
        short* qc = vc + TEN / sizeof(short);
        short* kc = qc + TEN / sizeof(short);
        __hip_bfloat16* Wb = (__hip_bfloat16*)(kc + TEN / sizeof(short));

        hipLaunchKernelGGL(wcvt_kernel, dim3(512), dim3(512), 0, stream, W, Wb);
        hipLaunchKernelGGL(conv_kernel, dim3(NB, 3), dim3(512), 0, stream,
                           q, k, v, cw, cb, qc, kc, vc);
        hipLaunchKernelGGL(attn_kernel, dim3(NB), dim3(512), 0, stream,
                           qc, kc, vc, mask, Wb, bo, (float*)d_out);
    } else {
        __hip_bfloat16* Wb = (__hip_bfloat16*)d_ws;
        hipLaunchKernelGGL(wcvt_kernel, dim3(512), dim3(512), 0, stream, W, Wb);
        hipLaunchKernelGGL(mha_fused4_kernel, dim3(NB), dim3(512), 0, stream,
                           q, k, v, mask, cw, cb, Wb, bo, (float*)d_out);
    }
}

// Round 6
// 648.158 us; speedup vs baseline: 8.2065x; 1.4420x over previous
//
#include <hip/hip_runtime.h>
#include <hip/hip_bf16.h>
#include <math.h>

#define NB 8192
#define NS 12
#define NH 8
#define NDK 64
#define NDM 512

typedef __attribute__((ext_vector_type(8))) short bf16x8;
typedef __attribute__((ext_vector_type(4))) float f32x4;

static __device__ __forceinline__ short f2bfb(float x) {
    __hip_bfloat16 h = __float2bfloat16(x);
    return *(short*)&h;
}
static __device__ __forceinline__ float bfb2f(short s) {
    unsigned u = ((unsigned)(unsigned short)s) << 16;
    return __uint_as_float(u);
}

__global__ __launch_bounds__(512) void wcvt_kernel(const float* __restrict__ W,
                                                   __hip_bfloat16* __restrict__ Wb) {
    int i = blockIdx.x * 512 + threadIdx.x;
    Wb[i] = __float2bfloat16(W[i]);
}

// ---------------- Kernel A: conv for one (batch, tensor) ----------------
// qc/kc layout: [B][H][12][64] bf16 ; vc layout: [B][H][64][12] bf16
__global__ __launch_bounds__(512) void conv_kernel(
    const float* __restrict__ gq, const float* __restrict__ gk, const float* __restrict__ gv,
    const float* __restrict__ gcw, const float* __restrict__ gcb,
    short* __restrict__ qc, short* __restrict__ kc, short* __restrict__ vc)
{
    __shared__ __align__(16) float xstage[NS][NDM];   // 24576 B
    __shared__ __align__(16) float wt[3][12][12];
    __shared__ __align__(16) float bconv[12];

    const int b   = blockIdx.x;
    const int t3  = blockIdx.y;          // 0=q, 1=k, 2=v
    const int tid = threadIdx.x;
    const int h   = tid >> 6;
    const int d   = tid & 63;

    if (tid < 432) {
        int t = tid / 144, rem = tid - t * 144;
        int s2 = rem / 12, s = rem - s2 * 12;
        wt[t][s2][s] = gcw[s * 36 + s2 * 3 + t];
    } else if (tid < 444) {
        bconv[tid - 432] = gcb[tid - 432];
    }

    const float* xb = ((t3 == 0) ? gq : (t3 == 1) ? gk : gv) + (size_t)b * (NS * NDM);
    {
        const float4* s4 = (const float4*)xb;
        float4* dst4 = (float4*)&xstage[0][0];
        #pragma unroll
        for (int i = 0; i < 3; ++i) dst4[tid + i * 512] = s4[tid + i * 512];
    }
    __syncthreads();

    f32x4 o0 = *(const f32x4*)&bconv[0];
    f32x4 o1 = *(const f32x4*)&bconv[4];
    f32x4 o2 = *(const f32x4*)&bconv[8];
    #pragma unroll 4
    for (int s2 = 0; s2 < 12; ++s2) {
        float c  = xstage[s2][h * 64 + d];
        float cm = (h > 0) ? xstage[s2][(h - 1) * 64 + d] : 0.f;
        float cp = (h < 7) ? xstage[s2][(h + 1) * 64 + d] : 0.f;
        float n0 = c + cm + cp;
        float nm = __shfl_up(n0, 1);   if (d == 0)  nm = 0.f;
        float np = __shfl_down(n0, 1); if (d == 63) np = 0.f;
        const f32x4* w0 = (const f32x4*)&wt[0][s2][0];
        const f32x4* w1 = (const f32x4*)&wt[1][s2][0];
        const f32x4* w2 = (const f32x4*)&wt[2][s2][0];
        o0 += w0[0] * nm + w1[0] * n0 + w2[0] * np;
        o1 += w0[1] * nm + w1[1] * n0 + w2[1] * np;
        o2 += w0[2] * nm + w1[2] * n0 + w2[2] * np;
    }

    if (t3 < 2) {
        short* dst = ((t3 == 0) ? qc : kc) + ((size_t)b * NH + h) * (NS * NDK);
        #pragma unroll
        for (int s = 0; s < 4; ++s) dst[s * 64 + d]       = f2bfb(o0[s]);
        #pragma unroll
        for (int s = 0; s < 4; ++s) dst[(s + 4) * 64 + d] = f2bfb(o1[s]);
        #pragma unroll
        for (int s = 0; s < 4; ++s) dst[(s + 8) * 64 + d] = f2bfb(o2[s]);
    } else {
        short* dst = vc + (((size_t)b * NH + h) * NDK + d) * NS;   // 12 contiguous bf16
        short4 p0, p1, p2;
        p0.x = f2bfb(o0[0]); p0.y = f2bfb(o0[1]); p0.z = f2bfb(o0[2]); p0.w = f2bfb(o0[3]);
        p1.x = f2bfb(o1[0]); p1.y = f2bfb(o1[1]); p1.z = f2bfb(o1[2]); p1.w = f2bfb(o1[3]);
        p2.x = f2bfb(o2[0]); p2.y = f2bfb(o2[1]); p2.z = f2bfb(o2[2]); p2.w = f2bfb(o2[3]);
        short4* d4 = (short4*)dst;
        d4[0] = p0; d4[1] = p1; d4[2] = p2;
    }
}

// ---------------- Kernel B: attention + projection for FOUR batches ----------------
__global__ __launch_bounds__(512) void attn2_kernel(
    const short* __restrict__ qc, const short* __restrict__ kc, const short* __restrict__ vc,
    const int* __restrict__ gmask, const __hip_bfloat16* __restrict__ Wb,
    const float* __restrict__ gbo, float* __restrict__ gout)
{
    __shared__ __align__(16) short abuf[48 * 520];      // 49920 B : A rows (4 batches x 12)
    __shared__ __align__(16) float probs[NH][12][16];   // 6144 B  : per-wave P buffer
    // ~56 KB -> 2 blocks/CU

    const int tid = threadIdx.x;
    const int w   = tid >> 6;
    const int ln  = tid & 63;
    const int d   = ln;
    const int rA  = ln & 15, g = ln >> 4;

    const int b0    = blockIdx.x * 4;
    const int bb    = w & 3;               // batch within block
    const int b     = b0 + bb;
    const int hbase = (w >> 2) * 4;        // 4 heads per wave

    const int rAr = (rA < 12) ? rA : 0;    // clamp pad rows (avoids OOB; masked anyway)

    // ---- attention phase: 4 (batch, head) tasks per wave ----
    for (int t = 0; t < 4; ++t) {
        const int h = hbase + t;
        const short* qs = qc + ((size_t)b * NH + h) * (NS * NDK);
        const short* ks = kc + ((size_t)b * NH + h) * (NS * NDK);
        bf16x8 aq0 = *(const bf16x8*)(qs + rAr * 64 + g * 8);
        bf16x8 aq1 = *(const bf16x8*)(qs + rAr * 64 + 32 + g * 8);
        bf16x8 bk0 = *(const bf16x8*)(ks + rAr * 64 + g * 8);
        bf16x8 bk1 = *(const bf16x8*)(ks + rAr * 64 + 32 + g * 8);
        f32x4 sc = {0.f, 0.f, 0.f, 0.f};
        sc = __builtin_amdgcn_mfma_f32_16x16x32_bf16(aq0, bk0, sc, 0, 0, 0);
        sc = __builtin_amdgcn_mfma_f32_16x16x32_bf16(aq1, bk1, sc, 0, 0, 0);

        float vv[12];
        {
            const short4* vp = (const short4*)(vc + (((size_t)b * NH + h) * NDK + d) * NS);
            short4 v0 = vp[0], v1 = vp[1], v2 = vp[2];
            vv[0] = bfb2f(v0.x); vv[1] = bfb2f(v0.y); vv[2]  = bfb2f(v0.z); vv[3]  = bfb2f(v0.w);
            vv[4] = bfb2f(v1.x); vv[5] = bfb2f(v1.y); vv[6]  = bfb2f(v1.z); vv[7]  = bfb2f(v1.w);
            vv[8] = bfb2f(v2.x); vv[9] = bfb2f(v2.y); vv[10] = bfb2f(v2.z); vv[11] = bfb2f(v2.w);
        }

        const int kj = rA;
        const int* mrow = gmask + (size_t)b * 144;
        #pragma unroll
        for (int r = 0; r < 4; ++r) {
            int qi = g * 4 + r;
            float s = sc[r] * 0.125f;
            if (kj >= 12) s = -INFINITY;
            else if (qi < 12 && mrow[qi * 12 + kj] == 0) s = -1e9f;
            float m = s;
            #pragma unroll
            for (int off = 1; off < 16; off <<= 1) m = fmaxf(m, __shfl_xor(m, off, 16));
            float e = __expf(s - m);
            float sum = e;
            #pragma unroll
            for (int off = 1; off < 16; off <<= 1) sum += __shfl_xor(sum, off, 16);
            if (qi < 12) probs[w][qi][kj] = e / sum;
        }

        #pragma unroll
        for (int qi = 0; qi < 12; ++qi) {
            const f32x4* pr = (const f32x4*)&probs[w][qi][0];
            f32x4 p0 = pr[0], p1 = pr[1], p2 = pr[2];
            float acc = 0.f;
            #pragma unroll
            for (int j = 0; j < 4; ++j) acc += p0[j] * vv[j] + p1[j] * vv[j + 4] + p2[j] * vv[j + 8];
            abuf[(bb * 12 + qi) * 520 + h * 64 + d] = f2bfb(acc);
        }
    }
    __syncthreads();

    // ---- GEMM phase: C[48 x 512] = A[48 x 512] * W^T, W-frag reused across 3 m-tiles ----
    {
        const short* Ws = (const short*)Wb;
        const int n_lane = w * 64 + rA;
        f32x4 acc[3][4] = {};
        #pragma unroll 4
        for (int kk = 0; kk < 16; ++kk) {
            int k0 = kk * 32 + g * 8;
            bf16x8 af0 = *(const bf16x8*)(abuf + (rA)      * 520 + k0);
            bf16x8 af1 = *(const bf16x8*)(abuf + (16 + rA) * 520 + k0);
            bf16x8 af2 = *(const bf16x8*)(abuf + (32 + rA) * 520 + k0);
            #pragma unroll
            for (int i = 0; i < 4; ++i) {
                bf16x8 bfg = *(const bf16x8*)(Ws + (size_t)(n_lane + i * 16) * NDM + k0);
                acc[0][i] = __builtin_amdgcn_mfma_f32_16x16x32_bf16(af0, bfg, acc[0][i], 0, 0, 0);
                acc[1][i] = __builtin_amdgcn_mfma_f32_16x16x32_bf16(af1, bfg, acc[1][i], 0, 0, 0);
                acc[2][i] = __builtin_amdgcn_mfma_f32_16x16x32_bf16(af2, bfg, acc[2][i], 0, 0, 0);
            }
        }
        float bias[4];
        #pragma unroll
        for (int i = 0; i < 4; ++i) bias[i] = gbo[w * 64 + i * 16 + rA];
        #pragma unroll
        for (int m = 0; m < 3; ++m) {
            #pragma unroll
            for (int i = 0; i < 4; ++i) {
                int n = w * 64 + i * 16 + rA;
                #pragma unroll
                for (int r = 0; r < 4; ++r) {
                    int mg  = m * 16 + g * 4 + r;       // 0..47
                    int bi  = mg / 12, qi = mg - bi * 12;
                    gout[(((size_t)(b0 + bi)) * NS + qi) * NDM + n] = acc[m][i][r] + bias[i];
                }
            }
        }
    }
}

// ---------------- Fallback: round-4 fused kernel (used if ws too small) ----------------
__global__ __launch_bounds__(512) void mha_fused4_kernel(
    const float* __restrict__ gq, const float* __restrict__ gk, const float* __restrict__ gv,
    const int* __restrict__ gmask, const float* __restrict__ gcw, const float* __restrict__ gcb,
    const __hip_bfloat16* __restrict__ Wb, const float* __restrict__ gbo,
    float* __restrict__ gout)
{
    __shared__ __align__(16) float xstage[NS][NDM];
    __shared__ __align__(16) short ovbuf[18432];
    __shared__ __align__(16) float probs[NH][16][16];
    __shared__ __align__(16) float wt[3][12][12];
    __shared__ __align__(16) float bconv[12];

    const int b   = blockIdx.x;
    const int tid = threadIdx.x;
    const int wv  = tid >> 6;
    const int ln  = tid & 63;
    const int h = wv, d = ln;

    if (tid < 432) {
        int t = tid / 144, rem = tid - t * 144;
        int s2 = rem / 12, s = rem - s2 * 12;
        wt[t][s2][s] = gcw[s * 36 + s2 * 3 + t];
    } else if (tid < 444) {
        bconv[tid - 432] = gcb[tid - 432];
    }

    const size_t xoff = (size_t)b * (NS * NDM);
    float vv[12];

    for (int t3 = 0; t3 < 3; ++t3) {
        const float* xb = ((t3 == 0) ? gq : (t3 == 1) ? gk : gv) + xoff;
        {
            const float4* s4 = (const float4*)xb;
            float4* dst4 = (float4*)&xstage[0][0];
            #pragma unroll
            for (int i = 0; i < 3; ++i) dst4[tid + i * 512] = s4[tid + i * 512];
        }
        __syncthreads();

        f32x4 o0 = *(const f32x4*)&bconv[0];
        f32x4 o1 = *(const f32x4*)&bconv[4];
        f32x4 o2 = *(const f32x4*)&bconv[8];
        #pragma unroll 4
        for (int s2 = 0; s2 < 12; ++s2) {
            float c  = xstage[s2][h * 64 + d];
            float cm = (h > 0) ? xstage[s2][(h - 1) * 64 + d] : 0.f;
            float cp = (h < 7) ? xstage[s2][(h + 1) * 64 + d] : 0.f;
            float n0 = c + cm + cp;
            float nm = __shfl_up(n0, 1);   if (d == 0)  nm = 0.f;
            float np = __shfl_down(n0, 1); if (d == 63) np = 0.f;
            const f32x4* w0 = (const f32x4*)&wt[0][s2][0];
            const f32x4* w1 = (const f32x4*)&wt[1][s2][0];
            const f32x4* w2 = (const f32x4*)&wt[2][s2][0];
            o0 += w0[0] * nm + w1[0] * n0 + w2[0] * np;
            o1 += w0[1] * nm + w1[1] * n0 + w2[1] * np;
            o2 += w0[2] * nm + w1[2] * n0 + w2[2] * np;
        }
        if (t3 < 2) {
            __hip_bfloat16* st = (__hip_bfloat16*)(ovbuf + (wv * 2 + t3) * 1152);
            #pragma unroll
            for (int s = 0; s < 4; ++s) st[s * 72 + d]       = __float2bfloat16(o0[s]);
            #pragma unroll
            for (int s = 0; s < 4; ++s) st[(s + 4) * 72 + d] = __float2bfloat16(o1[s]);
            #pragma unroll
            for (int s = 0; s < 4; ++s) st[(s + 8) * 72 + d] = __float2bfloat16(o2[s]);
            __syncthreads();
        } else {
            #pragma unroll
            for (int s = 0; s < 4; ++s) { vv[s] = o0[s]; vv[s + 4] = o1[s]; vv[s + 8] = o2[s]; }
        }
    }

    const short* qsp = ovbuf + (wv * 2 + 0) * 1152;
    const short* ksp = ovbuf + (wv * 2 + 1) * 1152;
    const int rA = ln & 15, g = ln >> 4;
    bf16x8 aq0 = *(const bf16x8*)(qsp + rA * 72 + g * 8);
    bf16x8 aq1 = *(const bf16x8*)(qsp + rA * 72 + 32 + g * 8);
    bf16x8 bk0 = *(const bf16x8*)(ksp + rA * 72 + g * 8);
    bf16x8 bk1 = *(const bf16x8*)(ksp + rA * 72 + 32 + g * 8);
    f32x4 sc = {0.f, 0.f, 0.f, 0.f};
    sc = __builtin_amdgcn_mfma_f32_16x16x32_bf16(aq0, bk0, sc, 0, 0, 0);
    sc = __builtin_amdgcn_mfma_f32_16x16x32_bf16(aq1, bk1, sc, 0, 0, 0);

    const int kj = rA;
    const int* mrow = gmask + (size_t)b * 144;
    #pragma unroll
    for (int r = 0; r < 4; ++r) {
        int qi = g * 4 + r;
        float s = sc[r] * 0.125f;
        if (kj >= 12) s = -INFINITY;
        else if (qi < 12 && mrow[qi * 12 + kj] == 0) s = -1e9f;
        float m = s;
        #pragma unroll
        for (int off = 1; off < 16; off <<= 1) m = fmaxf(m, __shfl_xor(m, off, 16));
        float e = __expf(s - m);
        float sum = e;
        #pragma unroll
        for (int off = 1; off < 16; off <<= 1) sum += __shfl_xor(sum, off, 16);
        probs[wv][qi][kj] = e / sum;
    }

    __syncthreads();

    __hip_bfloat16* ab = (__hip_bfloat16*)ovbuf;
    #pragma unroll
    for (int qi = 0; qi < 12; ++qi) {
        const f32x4* pr = (const f32x4*)&probs[wv][qi][0];
        f32x4 p0 = pr[0], p1 = pr[1], p2 = pr[2];
        float acc = 0.f;
        #pragma unroll
        for (int j = 0; j < 4; ++j) acc += p0[j] * vv[j] + p1[j] * vv[j + 4] + p2[j] * vv[j + 8];
        ab[qi * 520 + h * 64 + d] = __float2bfloat16(acc);
    }
    {
        unsigned* az = (unsigned*)(ovbuf + 12 * 520);
        for (int i = tid; i < 1040; i += 512) az[i] = 0u;
    }
    __syncthreads();

    {
        const short* Ws = (const short*)Wb;
        const short* As = ovbuf;
        f32x4 acc[4] = {};
        const int n_lane = wv * 64 + rA;
        #pragma unroll 4
        for (int kk = 0; kk < 16; ++kk) {
            int k0 = kk * 32 + g * 8;
            bf16x8 af = *(const bf16x8*)(As + rA * 520 + k0);
            #pragma unroll
            for (int i = 0; i < 4; ++i) {
                bf16x8 bfg = *(const bf16x8*)(Ws + (size_t)(n_lane + i * 16) * NDM + k0);
                acc[i] = __builtin_amdgcn_mfma_f32_16x16x32_bf16(af, bfg, acc[i], 0, 0, 0);
            }
        }
        float* outb = gout + (size_t)b * (NS * NDM);
        const int m0 = g * 4;
        #pragma unroll
        for (int i = 0; i < 4; ++i) {
            int n = wv * 64 + i * 16 + rA;
            float bias = gbo[n];
            #pragma unroll
            for (int r = 0; r < 4; ++r) {
                int m = m0 + r;
                if (m < 12) outb[m * NDM + n] = acc[i][r] + bias;
            }
        }
    }
}

extern "C" void kernel_launch(void* const* d_in, const int* in_sizes, int n_in,
                              void* d_out, int out_size, void* d_ws, size_t ws_size,
                              hipStream_t stream) {
    const float* q    = (const float*)d_in[0];
    const float* k    = (const float*)d_in[1];
    const float* v    = (const float*)d_in[2];
    const int*   mask = (const int*)d_in[3];
    const float* cw   = (const float*)d_in[4];
    const float* cb   = (const float*)d_in[5];
    const float* W    = (const float*)d_in[6];
    const float* bo   = (const float*)d_in[7];

    const size_t TEN = (size_t)NB * NH * NS * NDK * sizeof(short);  // 100,663,296 B per tensor
    const size_t REQ = 3 * TEN + (size_t)NDM * NDM * sizeof(short); // + 512 KB for Wb

    if (ws_size >= REQ) {
        short* vc = (short*)d_ws;
        short* qc = vc + TEN / sizeof(short);
        short* kc = qc + TEN / sizeof(short);
        __hip_bfloat16* Wb = (__hip_bfloat16*)(kc + TEN / sizeof(short));

        hipLaunchKernelGGL(wcvt_kernel, dim3(512), dim3(512), 0, stream, W, Wb);
        hipLaunchKernelGGL(conv_kernel, dim3(NB, 3), dim3(512), 0, stream,
                           q, k, v, cw, cb, qc, kc, vc);
        hipLaunchKernelGGL(attn2_kernel, dim3(NB / 4), dim3(512), 0, stream,
                           qc, kc, vc, mask, Wb, bo, (float*)d_out);
    } else {
        __hip_bfloat16* Wb = (__hip_bfloat16*)d_ws;
        hipLaunchKernelGGL(wcvt_kernel, dim3(512), dim3(512), 0, stream, W, Wb);
        hipLaunchKernelGGL(mha_fused4_kernel, dim3(NB), dim3(512), 0, stream,
                           q, k, v, mask, cw, cb, Wb, bo, (float*)d_out);
    }
}

// Round 7
// 635.274 us; speedup vs baseline: 8.3730x; 1.0203x over previous
//
#include <hip/hip_runtime.h>
#include <hip/hip_bf16.h>
#include <math.h>

#define NB 8192
#define NS 12
#define NH 8
#define NDK 64
#define NDM 512

typedef __attribute__((ext_vector_type(8))) short bf16x8;
typedef __attribute__((ext_vector_type(4))) float f32x4;

static __device__ __forceinline__ short f2bfb(float x) {
    __hip_bfloat16 h = __float2bfloat16(x);
    return *(short*)&h;
}
static __device__ __forceinline__ float bfb2f(short s) {
    unsigned u = ((unsigned)(unsigned short)s) << 16;
    return __uint_as_float(u);
}

// async global->LDS, 16B per lane; LDS dest is wave-uniform base (+lane*16 by HW)
static __device__ __forceinline__ void g2l16(const void* g, void* l) {
    __builtin_amdgcn_global_load_lds(
        (const __attribute__((address_space(1))) unsigned*)g,
        (__attribute__((address_space(3))) unsigned*)l, 16, 0, 0);
}

__global__ __launch_bounds__(512) void wcvt_kernel(const float* __restrict__ W,
                                                   __hip_bfloat16* __restrict__ Wb) {
    int i = blockIdx.x * 512 + threadIdx.x;
    Wb[i] = __float2bfloat16(W[i]);
}

// ---------------- Kernel A: pipelined conv, 8 tiles per block ----------------
// qc/kc layout: [B][H][12][64] bf16 ; vc layout: [B][H][64][12] bf16
#define TPB_TILES 8
__global__ __launch_bounds__(512) void conv2_kernel(
    const float* __restrict__ gq, const float* __restrict__ gk, const float* __restrict__ gv,
    const float* __restrict__ gcw, const float* __restrict__ gcb,
    short* __restrict__ qc, short* __restrict__ kc, short* __restrict__ vc)
{
    __shared__ __align__(16) float xstage[2][NS][NDM];   // 49152 B double buffer
    __shared__ __align__(16) float wt[3][12][12];        // [tap][in_ch][out_ch]
    __shared__ __align__(16) float bconv[12];
    // ~50.9 KB -> 3 blocks/CU

    const int tid = threadIdx.x;
    const int w   = tid >> 6;
    const int ln  = tid & 63;
    const int h = w, d = ln;

    if (tid < 432) {
        int t = tid / 144, rem = tid - t * 144;
        int s2 = rem / 12, s = rem - s2 * 12;
        wt[t][s2][s] = gcw[s * 36 + s2 * 3 + t];
    } else if (tid < 444) {
        bconv[tid - 432] = gcb[tid - 432];
    }

    const int t3 = blockIdx.x >> 10;                 // 1024 blocks per tensor
    const int b0 = (blockIdx.x & 1023) * TPB_TILES;
    const float* src = (t3 == 0) ? gq : (t3 == 1) ? gk : gv;

    // prologue: stage tile 0 into buffer 0 (3 x 1KB DMA per wave)
    {
        const char* g = (const char*)(src + (size_t)b0 * (NS * NDM)) + w * 3072 + ln * 16;
        char* l = (char*)&xstage[0][0][0] + w * 3072;
        #pragma unroll
        for (int j = 0; j < 3; ++j) g2l16(g + j * 1024, l + j * 1024);
    }

    for (int i = 0; i < TPB_TILES; ++i) {
        const int cur = i & 1, nxt = cur ^ 1;
        const int b = b0 + i;

        if (i + 1 < TPB_TILES) {
            // issue next tile's DMA, then wait only for CURRENT tile (keep 3 newest in flight)
            const char* g = (const char*)(src + (size_t)(b + 1) * (NS * NDM)) + w * 3072 + ln * 16;
            char* l = (char*)&xstage[nxt][0][0] + w * 3072;
            #pragma unroll
            for (int j = 0; j < 3; ++j) g2l16(g + j * 1024, l + j * 1024);
            asm volatile("s_waitcnt vmcnt(3) lgkmcnt(0)" ::: "memory");
        } else {
            asm volatile("s_waitcnt vmcnt(0) lgkmcnt(0)" ::: "memory");
        }
        __builtin_amdgcn_s_barrier();   // whole current buffer visible to all waves

        // ---- conv from xstage[cur] ----
        f32x4 o0 = *(const f32x4*)&bconv[0];
        f32x4 o1 = *(const f32x4*)&bconv[4];
        f32x4 o2 = *(const f32x4*)&bconv[8];
        #pragma unroll 4
        for (int s2 = 0; s2 < 12; ++s2) {
            float c  = xstage[cur][s2][h * 64 + d];
            float cm = (h > 0) ? xstage[cur][s2][(h - 1) * 64 + d] : 0.f;
            float cp = (h < 7) ? xstage[cur][s2][(h + 1) * 64 + d] : 0.f;
            float n0 = c + cm + cp;
            float nm = __shfl_up(n0, 1);   if (d == 0)  nm = 0.f;
            float np = __shfl_down(n0, 1); if (d == 63) np = 0.f;
            const f32x4* w0 = (const f32x4*)&wt[0][s2][0];
            const f32x4* w1 = (const f32x4*)&wt[1][s2][0];
            const f32x4* w2 = (const f32x4*)&wt[2][s2][0];
            o0 += w0[0] * nm + w1[0] * n0 + w2[0] * np;
            o1 += w0[1] * nm + w1[1] * n0 + w2[1] * np;
            o2 += w0[2] * nm + w1[2] * n0 + w2[2] * np;
        }

        if (t3 < 2) {
            short* dst = ((t3 == 0) ? qc : kc) + ((size_t)b * NH + h) * (NS * NDK);
            #pragma unroll
            for (int s = 0; s < 4; ++s) dst[s * 64 + d]       = f2bfb(o0[s]);
            #pragma unroll
            for (int s = 0; s < 4; ++s) dst[(s + 4) * 64 + d] = f2bfb(o1[s]);
            #pragma unroll
            for (int s = 0; s < 4; ++s) dst[(s + 8) * 64 + d] = f2bfb(o2[s]);
        } else {
            short* dst = vc + (((size_t)b * NH + h) * NDK + d) * NS;
            short4 p0, p1, p2;
            p0.x = f2bfb(o0[0]); p0.y = f2bfb(o0[1]); p0.z = f2bfb(o0[2]); p0.w = f2bfb(o0[3]);
            p1.x = f2bfb(o1[0]); p1.y = f2bfb(o1[1]); p1.z = f2bfb(o1[2]); p1.w = f2bfb(o1[3]);
            p2.x = f2bfb(o2[0]); p2.y = f2bfb(o2[1]); p2.z = f2bfb(o2[2]); p2.w = f2bfb(o2[3]);
            short4* d4 = (short4*)dst;
            d4[0] = p0; d4[1] = p1; d4[2] = p2;
        }

        __builtin_amdgcn_s_barrier();   // all reads of xstage[cur] done before it is re-DMA'd
    }
}

// ---------------- Kernel B: attention + projection for FOUR batches ----------------
__global__ __launch_bounds__(512) void attn2_kernel(
    const short* __restrict__ qc, const short* __restrict__ kc, const short* __restrict__ vc,
    const int* __restrict__ gmask, const __hip_bfloat16* __restrict__ Wb,
    const float* __restrict__ gbo, float* __restrict__ gout)
{
    __shared__ __align__(16) short abuf[48 * 520];      // 49920 B : A rows (4 batches x 12)
    __shared__ __align__(16) float probs[NH][12][16];   // 6144 B

    const int tid = threadIdx.x;
    const int w   = tid >> 6;
    const int ln  = tid & 63;
    const int d   = ln;
    const int rA  = ln & 15, g = ln >> 4;

    const int b0    = blockIdx.x * 4;
    const int bb    = w & 3;
    const int b     = b0 + bb;
    const int hbase = (w >> 2) * 4;

    const int rAr = (rA < 12) ? rA : 0;

    for (int t = 0; t < 4; ++t) {
        const int h = hbase + t;
        const short* qs = qc + ((size_t)b * NH + h) * (NS * NDK);
        const short* ks = kc + ((size_t)b * NH + h) * (NS * NDK);
        bf16x8 aq0 = *(const bf16x8*)(qs + rAr * 64 + g * 8);
        bf16x8 aq1 = *(const bf16x8*)(qs + rAr * 64 + 32 + g * 8);
        bf16x8 bk0 = *(const bf16x8*)(ks + rAr * 64 + g * 8);
        bf16x8 bk1 = *(const bf16x8*)(ks + rAr * 64 + 32 + g * 8);
        f32x4 sc = {0.f, 0.f, 0.f, 0.f};
        sc = __builtin_amdgcn_mfma_f32_16x16x32_bf16(aq0, bk0, sc, 0, 0, 0);
        sc = __builtin_amdgcn_mfma_f32_16x16x32_bf16(aq1, bk1, sc, 0, 0, 0);

        float vv[12];
        {
            const short4* vp = (const short4*)(vc + (((size_t)b * NH + h) * NDK + d) * NS);
            short4 v0 = vp[0], v1 = vp[1], v2 = vp[2];
            vv[0] = bfb2f(v0.x); vv[1] = bfb2f(v0.y); vv[2]  = bfb2f(v0.z); vv[3]  = bfb2f(v0.w);
            vv[4] = bfb2f(v1.x); vv[5] = bfb2f(v1.y); vv[6]  = bfb2f(v1.z); vv[7]  = bfb2f(v1.w);
            vv[8] = bfb2f(v2.x); vv[9] = bfb2f(v2.y); vv[10] = bfb2f(v2.z); vv[11] = bfb2f(v2.w);
        }

        const int kj = rA;
        const int* mrow = gmask + (size_t)b * 144;
        #pragma unroll
        for (int r = 0; r < 4; ++r) {
            int qi = g * 4 + r;
            float s = sc[r] * 0.125f;
            if (kj >= 12) s = -INFINITY;
            else if (qi < 12 && mrow[qi * 12 + kj] == 0) s = -1e9f;
            float m = s;
            #pragma unroll
            for (int off = 1; off < 16; off <<= 1) m = fmaxf(m, __shfl_xor(m, off, 16));
            float e = __expf(s - m);
            float sum = e;
            #pragma unroll
            for (int off = 1; off < 16; off <<= 1) sum += __shfl_xor(sum, off, 16);
            if (qi < 12) probs[w][qi][kj] = e / sum;
        }

        #pragma unroll
        for (int qi = 0; qi < 12; ++qi) {
            const f32x4* pr = (const f32x4*)&probs[w][qi][0];
            f32x4 p0 = pr[0], p1 = pr[1], p2 = pr[2];
            float acc = 0.f;
            #pragma unroll
            for (int j = 0; j < 4; ++j) acc += p0[j] * vv[j] + p1[j] * vv[j + 4] + p2[j] * vv[j + 8];
            abuf[(bb * 12 + qi) * 520 + h * 64 + d] = f2bfb(acc);
        }
    }
    __syncthreads();

    {
        const short* Ws = (const short*)Wb;
        const int n_lane = w * 64 + rA;
        f32x4 acc[3][4] = {};
        #pragma unroll 4
        for (int kk = 0; kk < 16; ++kk) {
            int k0 = kk * 32 + g * 8;
            bf16x8 af0 = *(const bf16x8*)(abuf + (rA)      * 520 + k0);
            bf16x8 af1 = *(const bf16x8*)(abuf + (16 + rA) * 520 + k0);
            bf16x8 af2 = *(const bf16x8*)(abuf + (32 + rA) * 520 + k0);
            #pragma unroll
            for (int i = 0; i < 4; ++i) {
                bf16x8 bfg = *(const bf16x8*)(Ws + (size_t)(n_lane + i * 16) * NDM + k0);
                acc[0][i] = __builtin_amdgcn_mfma_f32_16x16x32_bf16(af0, bfg, acc[0][i], 0, 0, 0);
                acc[1][i] = __builtin_amdgcn_mfma_f32_16x16x32_bf16(af1, bfg, acc[1][i], 0, 0, 0);
                acc[2][i] = __builtin_amdgcn_mfma_f32_16x16x32_bf16(af2, bfg, acc[2][i], 0, 0, 0);
            }
        }
        float bias[4];
        #pragma unroll
        for (int i = 0; i < 4; ++i) bias[i] = gbo[w * 64 + i * 16 + rA];
        #pragma unroll
        for (int m = 0; m < 3; ++m) {
            #pragma unroll
            for (int i = 0; i < 4; ++i) {
                int n = w * 64 + i * 16 + rA;
                #pragma unroll
                for (int r = 0; r < 4; ++r) {
                    int mg  = m * 16 + g * 4 + r;
                    int bi  = mg / 12, qi = mg - bi * 12;
                    gout[(((size_t)(b0 + bi)) * NS + qi) * NDM + n] = acc[m][i][r] + bias[i];
                }
            }
        }
    }
}

// ---------------- Fallback: fused kernel (used if ws too small) ----------------
__global__ __launch_bounds__(512) void mha_fused4_kernel(
    const float* __restrict__ gq, const float* __restrict__ gk, const float* __restrict__ gv,
    const int* __restrict__ gmask, const float* __restrict__ gcw, const float* __restrict__ gcb,
    const __hip_bfloat16* __restrict__ Wb, const float* __restrict__ gbo,
    float* __restrict__ gout)
{
    __shared__ __align__(16) float xstage[NS][NDM];
    __shared__ __align__(16) short ovbuf[18432];
    __shared__ __align__(16) float probs[NH][16][16];
    __shared__ __align__(16) float wt[3][12][12];
    __shared__ __align__(16) float bconv[12];

    const int b   = blockIdx.x;
    const int tid = threadIdx.x;
    const int wv  = tid >> 6;
    const int ln  = tid & 63;
    const int h = wv, d = ln;

    if (tid < 432) {
        int t = tid / 144, rem = tid - t * 144;
        int s2 = rem / 12, s = rem - s2 * 12;
        wt[t][s2][s] = gcw[s * 36 + s2 * 3 + t];
    } else if (tid < 444) {
        bconv[tid - 432] = gcb[tid - 432];
    }

    const size_t xoff = (size_t)b * (NS * NDM);
    float vv[12];

    for (int t3 = 0; t3 < 3; ++t3) {
        const float* xb = ((t3 == 0) ? gq : (t3 == 1) ? gk : gv) + xoff;
        {
            const float4* s4 = (const float4*)xb;
            float4* dst4 = (float4*)&xstage[0][0];
            #pragma unroll
            for (int i = 0; i < 3; ++i) dst4[tid + i * 512] = s4[tid + i * 512];
        }
        __syncthreads();

        f32x4 o0 = *(const f32x4*)&bconv[0];
        f32x4 o1 = *(const f32x4*)&bconv[4];
        f32x4 o2 = *(const f32x4*)&bconv[8];
        #pragma unroll 4
        for (int s2 = 0; s2 < 12; ++s2) {
            float c  = xstage[s2][h * 64 + d];
            float cm = (h > 0) ? xstage[s2][(h - 1) * 64 + d] : 0.f;
            float cp = (h < 7) ? xstage[s2][(h + 1) * 64 + d] : 0.f;
            float n0 = c + cm + cp;
            float nm = __shfl_up(n0, 1);   if (d == 0)  nm = 0.f;
            float np = __shfl_down(n0, 1); if (d == 63) np = 0.f;
            const f32x4* w0 = (const f32x4*)&wt[0][s2][0];
            const f32x4* w1 = (const f32x4*)&wt[1][s2][0];
            const f32x4* w2 = (const f32x4*)&wt[2][s2][0];
            o0 += w0[0] * nm + w1[0] * n0 + w2[0] * np;
            o1 += w0[1] * nm + w1[1] * n0 + w2[1] * np;
            o2 += w0[2] * nm + w1[2] * n0 + w2[2] * np;
        }
        if (t3 < 2) {
            __hip_bfloat16* st = (__hip_bfloat16*)(ovbuf + (wv * 2 + t3) * 1152);
            #pragma unroll
            for (int s = 0; s < 4; ++s) st[s * 72 + d]       = __float2bfloat16(o0[s]);
            #pragma unroll
            for (int s = 0; s < 4; ++s) st[(s + 4) * 72 + d] = __float2bfloat16(o1[s]);
            #pragma unroll
            for (int s = 0; s < 4; ++s) st[(s + 8) * 72 + d] = __float2bfloat16(o2[s]);
            __syncthreads();
        } else {
            #pragma unroll
            for (int s = 0; s < 4; ++s) { vv[s] = o0[s]; vv[s + 4] = o1[s]; vv[s + 8] = o2[s]; }
        }
    }

    const short* qsp = ovbuf + (wv * 2 + 0) * 1152;
    const short* ksp = ovbuf + (wv * 2 + 1) * 1152;
    const int rA = ln & 15, g = ln >> 4;
    bf16x8 aq0 = *(const bf16x8*)(qsp + rA * 72 + g * 8);
    bf16x8 aq1 = *(const bf16x8*)(qsp + rA * 72 + 32 + g * 8);
    bf16x8 bk0 = *(const bf16x8*)(ksp + rA * 72 + g * 8);
    bf16x8 bk1 = *(const bf16x8*)(ksp + rA * 72 + 32 + g * 8);
    f32x4 sc = {0.f, 0.f, 0.f, 0.f};
    sc = __builtin_amdgcn_mfma_f32_16x16x32_bf16(aq0, bk0, sc, 0, 0, 0);
    sc = __builtin_amdgcn_mfma_f32_16x16x32_bf16(aq1, bk1, sc, 0, 0, 0);

    const int kj = rA;
    const int* mrow = gmask + (size_t)b * 144;
    #pragma unroll
    for (int r = 0; r < 4; ++r) {
        int qi = g * 4 + r;
        float s = sc[r] * 0.125f;
        if (kj >= 12) s = -INFINITY;
        else if (qi < 12 && mrow[qi * 12 + kj] == 0) s = -1e9f;
        float m = s;
        #pragma unroll
        for (int off = 1; off < 16; off <<= 1) m = fmaxf(m, __shfl_xor(m, off, 16));
        float e = __expf(s - m);
        float sum = e;
        #pragma unroll
        for (int off = 1; off < 16; off <<= 1) sum += __shfl_xor(sum, off, 16);
        probs[wv][qi][kj] = e / sum;
    }

    __syncthreads();

    __hip_bfloat16* ab = (__hip_bfloat16*)ovbuf;
    #pragma unroll
    for (int qi = 0; qi < 12; ++qi) {
        const f32x4* pr = (const f32x4*)&probs[wv][qi][0];
        f32x4 p0 = pr[0], p1 = pr[1], p2 = pr[2];
        float acc = 0.f;
        #pragma unroll
        for (int j = 0; j < 4; ++j) acc += p0[j] * vv[j] + p1[j] * vv[j + 4] + p2[j] * vv[j + 8];
        ab[qi * 520 + h * 64 + d] = __float2bfloat16(acc);
    }
    {
        unsigned* az = (unsigned*)(ovbuf + 12 * 520);
        for (int i = tid; i < 1040; i += 512) az[i] = 0u;
    }
    __syncthreads();

    {
        const short* Ws = (const short*)Wb;
        const short* As = ovbuf;
        f32x4 acc[4] = {};
        const int n_lane = wv * 64 + rA;
        #pragma unroll 4
        for (int kk = 0; kk < 16; ++kk) {
            int k0 = kk * 32 + g * 8;
            bf16x8 af = *(const bf16x8*)(As + rA * 520 + k0);
            #pragma unroll
            for (int i = 0; i < 4; ++i) {
                bf16x8 bfg = *(const bf16x8*)(Ws + (size_t)(n_lane + i * 16) * NDM + k0);
                acc[i] = __builtin_amdgcn_mfma_f32_16x16x32_bf16(af, bfg, acc[i], 0, 0, 0);
            }
        }
        float* outb = gout + (size_t)b * (NS * NDM);
        const int m0 = g * 4;
        #pragma unroll
        for (int i = 0; i < 4; ++i) {
            int n = wv * 64 + i * 16 + rA;
            float bias = gbo[n];
            #pragma unroll
            for (int r = 0; r < 4; ++r) {
                int m = m0 + r;
                if (m < 12) outb[m * NDM + n] = acc[i][r] + bias;
            }
        }
    }
}

extern "C" void kernel_launch(void* const* d_in, const int* in_sizes, int n_in,
                              void* d_out, int out_size, void* d_ws, size_t ws_size,
                              hipStream_t stream) {
    const float* q    = (const float*)d_in[0];
    const float* k    = (const float*)d_in[1];
    const float* v    = (const float*)d_in[2];
    const int*   mask = (const int*)d_in[3];
    const float* cw   = (const float*)d_in[4];
    const float* cb   = (const float*)d_in[5];
    const float* W    = (const float*)d_in[6];
    const float* bo   = (const float*)d_in[7];

    const size_t TEN = (size_t)NB * NH * NS * NDK * sizeof(short);
    const size_t REQ = 3 * TEN + (size_t)NDM * NDM * sizeof(short);

    if (ws_size >= REQ) {
        short* vc = (short*)d_ws;
        short* qc = vc + TEN / sizeof(short);
        short* kc = qc + TEN / sizeof(short);
        __hip_bfloat16* Wb = (__hip_bfloat16*)(kc + TEN / sizeof(short));

        hipLaunchKernelGGL(wcvt_kernel, dim3(512), dim3(512), 0, stream, W, Wb);
        hipLaunchKernelGGL(conv2_kernel, dim3(3 * NB / TPB_TILES), dim3(512), 0, stream,
                           q, k, v, cw, cb, qc, kc, vc);
        hipLaunchKernelGGL(attn2_kernel, dim3(NB / 4), dim3(512), 0, stream,
                           qc, kc, vc, mask, Wb, bo, (float*)d_out);
    } else {
        __hip_bfloat16* Wb = (__hip_bfloat16*)d_ws;
        hipLaunchKernelGGL(wcvt_kernel, dim3(512), dim3(512), 0, stream, W, Wb);
        hipLaunchKernelGGL(mha_fused4_kernel, dim3(NB), dim3(512), 0, stream,
                           q, k, v, mask, cw, cb, Wb, bo, (float*)d_out);
    }
}

// Round 8
// 531.613 us; speedup vs baseline: 10.0057x; 1.1950x over previous
//
#include <hip/hip_runtime.h>
#include <hip/hip_bf16.h>
#include <math.h>

#define NB 8192
#define NS 12
#define NH 8
#define NDK 64
#define NDM 512

typedef __attribute__((ext_vector_type(8))) short bf16x8;
typedef __attribute__((ext_vector_type(4))) float f32x4;

static __device__ __forceinline__ short f2bfb(float x) {
    __hip_bfloat16 h = __float2bfloat16(x);
    return *(short*)&h;
}
static __device__ __forceinline__ float bfb2f(short s) {
    unsigned u = ((unsigned)(unsigned short)s) << 16;
    return __uint_as_float(u);
}

__global__ __launch_bounds__(512) void wcvt_kernel(const float* __restrict__ W,
                                                   __hip_bfloat16* __restrict__ Wb) {
    int i = blockIdx.x * 512 + threadIdx.x;
    Wb[i] = __float2bfloat16(W[i]);
}

// ---------------- Kernel A: barrier-free streaming conv ----------------
// thread = (b, h, d); neighbors in h read straight from global (L1-cached),
// neighbors in d via shfl. No x staging, no per-tile barriers.
// qc/kc layout: [B][H][12][64] bf16 ; vc layout: [B][H][64][12] bf16
__global__ __launch_bounds__(256) void conv3_kernel(
    const float* __restrict__ gq, const float* __restrict__ gk, const float* __restrict__ gv,
    const float* __restrict__ gcw, const float* __restrict__ gcb,
    short* __restrict__ qc, short* __restrict__ kc, short* __restrict__ vc)
{
    __shared__ __align__(16) float wt[3][12][12];   // [tap][in_ch][out_ch]
    __shared__ __align__(16) float bconv[12];

    const int tid = threadIdx.x;
    for (int i = tid; i < 444; i += 256) {
        if (i < 432) {
            int t = i / 144, rem = i - t * 144;
            int s2 = rem / 12, s = rem - s2 * 12;
            wt[t][s2][s] = gcw[s * 36 + s2 * 3 + t];
        } else {
            bconv[i - 432] = gcb[i - 432];
        }
    }
    __syncthreads();

    const int t3   = blockIdx.y;                    // 0=q, 1=k, 2=v
    const int flat = blockIdx.x * 256 + tid;        // over B*H*DK = 8192*512
    const int b    = flat >> 9;
    const int hd   = flat & 511;
    const int h    = hd >> 6;
    const int d    = hd & 63;

    const float* src = (t3 == 0) ? gq : (t3 == 1) ? gk : gv;
    const float* xb  = src + (size_t)b * (NS * NDM);

    const float fm = (h > 0) ? 1.f : 0.f;
    const float fp = (h < 7) ? 1.f : 0.f;
    const float* pa = xb + h * 64 + d;
    const float* pm = xb + (h > 0 ? h - 1 : h) * 64 + d;   // clamped (in-bounds), zeroed by fm
    const float* pp = xb + (h < 7 ? h + 1 : h) * 64 + d;

    f32x4 o0 = *(const f32x4*)&bconv[0];
    f32x4 o1 = *(const f32x4*)&bconv[4];
    f32x4 o2 = *(const f32x4*)&bconv[8];

    #pragma unroll 3
    for (int s2 = 0; s2 < 12; ++s2) {
        float a  = pa[s2 * 512];
        float am = pm[s2 * 512] * fm;
        float ap = pp[s2 * 512] * fp;
        float n0 = a + am + ap;
        float nm = __shfl_up(n0, 1);   if (d == 0)  nm = 0.f;   // zero-pad d=-1
        float np = __shfl_down(n0, 1); if (d == 63) np = 0.f;   // zero-pad d=64
        const f32x4* w0 = (const f32x4*)&wt[0][s2][0];
        const f32x4* w1 = (const f32x4*)&wt[1][s2][0];
        const f32x4* w2 = (const f32x4*)&wt[2][s2][0];
        o0 += w0[0] * nm + w1[0] * n0 + w2[0] * np;
        o1 += w0[1] * nm + w1[1] * n0 + w2[1] * np;
        o2 += w0[2] * nm + w1[2] * n0 + w2[2] * np;
    }

    if (t3 < 2) {
        short* dst = ((t3 == 0) ? qc : kc) + ((size_t)b * NH + h) * (NS * NDK);
        #pragma unroll
        for (int s = 0; s < 4; ++s) dst[s * 64 + d]       = f2bfb(o0[s]);
        #pragma unroll
        for (int s = 0; s < 4; ++s) dst[(s + 4) * 64 + d] = f2bfb(o1[s]);
        #pragma unroll
        for (int s = 0; s < 4; ++s) dst[(s + 8) * 64 + d] = f2bfb(o2[s]);
    } else {
        short* dst = vc + (((size_t)b * NH + h) * NDK + d) * NS;   // 12 contiguous bf16
        short4 p0, p1, p2;
        p0.x = f2bfb(o0[0]); p0.y = f2bfb(o0[1]); p0.z = f2bfb(o0[2]); p0.w = f2bfb(o0[3]);
        p1.x = f2bfb(o1[0]); p1.y = f2bfb(o1[1]); p1.z = f2bfb(o1[2]); p1.w = f2bfb(o1[3]);
        p2.x = f2bfb(o2[0]); p2.y = f2bfb(o2[1]); p2.z = f2bfb(o2[2]); p2.w = f2bfb(o2[3]);
        short4* d4 = (short4*)dst;
        d4[0] = p0; d4[1] = p1; d4[2] = p2;
    }
}

// ---------------- Kernel B: attention + projection for FOUR batches ----------------
__global__ __launch_bounds__(512) void attn2_kernel(
    const short* __restrict__ qc, const short* __restrict__ kc, const short* __restrict__ vc,
    const int* __restrict__ gmask, const __hip_bfloat16* __restrict__ Wb,
    const float* __restrict__ gbo, float* __restrict__ gout)
{
    __shared__ __align__(16) short abuf[48 * 520];      // 49920 B
    __shared__ __align__(16) float probs[NH][12][16];   // 6144 B

    const int tid = threadIdx.x;
    const int w   = tid >> 6;
    const int ln  = tid & 63;
    const int d   = ln;
    const int rA  = ln & 15, g = ln >> 4;

    const int b0    = blockIdx.x * 4;
    const int bb    = w & 3;
    const int b     = b0 + bb;
    const int hbase = (w >> 2) * 4;

    const int rAr = (rA < 12) ? rA : 0;

    for (int t = 0; t < 4; ++t) {
        const int h = hbase + t;
        const short* qs = qc + ((size_t)b * NH + h) * (NS * NDK);
        const short* ks = kc + ((size_t)b * NH + h) * (NS * NDK);
        bf16x8 aq0 = *(const bf16x8*)(qs + rAr * 64 + g * 8);
        bf16x8 aq1 = *(const bf16x8*)(qs + rAr * 64 + 32 + g * 8);
        bf16x8 bk0 = *(const bf16x8*)(ks + rAr * 64 + g * 8);
        bf16x8 bk1 = *(const bf16x8*)(ks + rAr * 64 + 32 + g * 8);
        f32x4 sc = {0.f, 0.f, 0.f, 0.f};
        sc = __builtin_amdgcn_mfma_f32_16x16x32_bf16(aq0, bk0, sc, 0, 0, 0);
        sc = __builtin_amdgcn_mfma_f32_16x16x32_bf16(aq1, bk1, sc, 0, 0, 0);

        float vv[12];
        {
            const short4* vp = (const short4*)(vc + (((size_t)b * NH + h) * NDK + d) * NS);
            short4 v0 = vp[0], v1 = vp[1], v2 = vp[2];
            vv[0] = bfb2f(v0.x); vv[1] = bfb2f(v0.y); vv[2]  = bfb2f(v0.z); vv[3]  = bfb2f(v0.w);
            vv[4] = bfb2f(v1.x); vv[5] = bfb2f(v1.y); vv[6]  = bfb2f(v1.z); vv[7]  = bfb2f(v1.w);
            vv[8] = bfb2f(v2.x); vv[9] = bfb2f(v2.y); vv[10] = bfb2f(v2.z); vv[11] = bfb2f(v2.w);
        }

        const int kj = rA;
        const int* mrow = gmask + (size_t)b * 144;
        #pragma unroll
        for (int r = 0; r < 4; ++r) {
            int qi = g * 4 + r;
            float s = sc[r] * 0.125f;
            if (kj >= 12) s = -INFINITY;
            else if (qi < 12 && mrow[qi * 12 + kj] == 0) s = -1e9f;
            float m = s;
            #pragma unroll
            for (int off = 1; off < 16; off <<= 1) m = fmaxf(m, __shfl_xor(m, off, 16));
            float e = __expf(s - m);
            float sum = e;
            #pragma unroll
            for (int off = 1; off < 16; off <<= 1) sum += __shfl_xor(sum, off, 16);
            if (qi < 12) probs[w][qi][kj] = e / sum;
        }

        #pragma unroll
        for (int qi = 0; qi < 12; ++qi) {
            const f32x4* pr = (const f32x4*)&probs[w][qi][0];
            f32x4 p0 = pr[0], p1 = pr[1], p2 = pr[2];
            float acc = 0.f;
            #pragma unroll
            for (int j = 0; j < 4; ++j) acc += p0[j] * vv[j] + p1[j] * vv[j + 4] + p2[j] * vv[j + 8];
            abuf[(bb * 12 + qi) * 520 + h * 64 + d] = f2bfb(acc);
        }
    }
    __syncthreads();

    {
        const short* Ws = (const short*)Wb;
        const int n_lane = w * 64 + rA;
        f32x4 acc[3][4] = {};
        #pragma unroll 4
        for (int kk = 0; kk < 16; ++kk) {
            int k0 = kk * 32 + g * 8;
            bf16x8 af0 = *(const bf16x8*)(abuf + (rA)      * 520 + k0);
            bf16x8 af1 = *(const bf16x8*)(abuf + (16 + rA) * 520 + k0);
            bf16x8 af2 = *(const bf16x8*)(abuf + (32 + rA) * 520 + k0);
            #pragma unroll
            for (int i = 0; i < 4; ++i) {
                bf16x8 bfg = *(const bf16x8*)(Ws + (size_t)(n_lane + i * 16) * NDM + k0);
                acc[0][i] = __builtin_amdgcn_mfma_f32_16x16x32_bf16(af0, bfg, acc[0][i], 0, 0, 0);
                acc[1][i] = __builtin_amdgcn_mfma_f32_16x16x32_bf16(af1, bfg, acc[1][i], 0, 0, 0);
                acc[2][i] = __builtin_amdgcn_mfma_f32_16x16x32_bf16(af2, bfg, acc[2][i], 0, 0, 0);
            }
        }
        float bias[4];
        #pragma unroll
        for (int i = 0; i < 4; ++i) bias[i] = gbo[w * 64 + i * 16 + rA];
        #pragma unroll
        for (int m = 0; m < 3; ++m) {
            #pragma unroll
            for (int i = 0; i < 4; ++i) {
                int n = w * 64 + i * 16 + rA;
                #pragma unroll
                for (int r = 0; r < 4; ++r) {
                    int mg  = m * 16 + g * 4 + r;
                    int bi  = mg / 12, qi = mg - bi * 12;
                    gout[(((size_t)(b0 + bi)) * NS + qi) * NDM + n] = acc[m][i][r] + bias[i];
                }
            }
        }
    }
}

// ---------------- Fallback: fused kernel (used if ws too small) ----------------
__global__ __launch_bounds__(512) void mha_fused4_kernel(
    const float* __restrict__ gq, const float* __restrict__ gk, const float* __restrict__ gv,
    const int* __restrict__ gmask, const float* __restrict__ gcw, const float* __restrict__ gcb,
    const __hip_bfloat16* __restrict__ Wb, const float* __restrict__ gbo,
    float* __restrict__ gout)
{
    __shared__ __align__(16) float xstage[NS][NDM];
    __shared__ __align__(16) short ovbuf[18432];
    __shared__ __align__(16) float probs[NH][16][16];
    __shared__ __align__(16) float wt[3][12][12];
    __shared__ __align__(16) float bconv[12];

    const int b   = blockIdx.x;
    const int tid = threadIdx.x;
    const int wv  = tid >> 6;
    const int ln  = tid & 63;
    const int h = wv, d = ln;

    if (tid < 432) {
        int t = tid / 144, rem = tid - t * 144;
        int s2 = rem / 12, s = rem - s2 * 12;
        wt[t][s2][s] = gcw[s * 36 + s2 * 3 + t];
    } else if (tid < 444) {
        bconv[tid - 432] = gcb[tid - 432];
    }

    const size_t xoff = (size_t)b * (NS * NDM);
    float vv[12];

    for (int t3 = 0; t3 < 3; ++t3) {
        const float* xb = ((t3 == 0) ? gq : (t3 == 1) ? gk : gv) + xoff;
        {
            const float4* s4 = (const float4*)xb;
            float4* dst4 = (float4*)&xstage[0][0];
            #pragma unroll
            for (int i = 0; i < 3; ++i) dst4[tid + i * 512] = s4[tid + i * 512];
        }
        __syncthreads();

        f32x4 o0 = *(const f32x4*)&bconv[0];
        f32x4 o1 = *(const f32x4*)&bconv[4];
        f32x4 o2 = *(const f32x4*)&bconv[8];
        #pragma unroll 4
        for (int s2 = 0; s2 < 12; ++s2) {
            float c  = xstage[s2][h * 64 + d];
            float cm = (h > 0) ? xstage[s2][(h - 1) * 64 + d] : 0.f;
            float cp = (h < 7) ? xstage[s2][(h + 1) * 64 + d] : 0.f;
            float n0 = c + cm + cp;
            float nm = __shfl_up(n0, 1);   if (d == 0)  nm = 0.f;
            float np = __shfl_down(n0, 1); if (d == 63) np = 0.f;
            const f32x4* w0 = (const f32x4*)&wt[0][s2][0];
            const f32x4* w1 = (const f32x4*)&wt[1][s2][0];
            const f32x4* w2 = (const f32x4*)&wt[2][s2][0];
            o0 += w0[0] * nm + w1[0] * n0 + w2[0] * np;
            o1 += w0[1] * nm + w1[1] * n0 + w2[1] * np;
            o2 += w0[2] * nm + w1[2] * n0 + w2[2] * np;
        }
        if (t3 < 2) {
            __hip_bfloat16* st = (__hip_bfloat16*)(ovbuf + (wv * 2 + t3) * 1152);
            #pragma unroll
            for (int s = 0; s < 4; ++s) st[s * 72 + d]       = __float2bfloat16(o0[s]);
            #pragma unroll
            for (int s = 0; s < 4; ++s) st[(s + 4) * 72 + d] = __float2bfloat16(o1[s]);
            #pragma unroll
            for (int s = 0; s < 4; ++s) st[(s + 8) * 72 + d] = __float2bfloat16(o2[s]);
            __syncthreads();
        } else {
            #pragma unroll
            for (int s = 0; s < 4; ++s) { vv[s] = o0[s]; vv[s + 4] = o1[s]; vv[s + 8] = o2[s]; }
        }
    }

    const short* qsp = ovbuf + (wv * 2 + 0) * 1152;
    const short* ksp = ovbuf + (wv * 2 + 1) * 1152;
    const int rA = ln & 15, g = ln >> 4;
    bf16x8 aq0 = *(const bf16x8*)(qsp + rA * 72 + g * 8);
    bf16x8 aq1 = *(const bf16x8*)(qsp + rA * 72 + 32 + g * 8);
    bf16x8 bk0 = *(const bf16x8*)(ksp + rA * 72 + g * 8);
    bf16x8 bk1 = *(const bf16x8*)(ksp + rA * 72 + 32 + g * 8);
    f32x4 sc = {0.f, 0.f, 0.f, 0.f};
    sc = __builtin_amdgcn_mfma_f32_16x16x32_bf16(aq0, bk0, sc, 0, 0, 0);
    sc = __builtin_amdgcn_mfma_f32_16x16x32_bf16(aq1, bk1, sc, 0, 0, 0);

    const int kj = rA;
    const int* mrow = gmask + (size_t)b * 144;
    #pragma unroll
    for (int r = 0; r < 4; ++r) {
        int qi = g * 4 + r;
        float s = sc[r] * 0.125f;
        if (kj >= 12) s = -INFINITY;
        else if (qi < 12 && mrow[qi * 12 + kj] == 0) s = -1e9f;
        float m = s;
        #pragma unroll
        for (int off = 1; off < 16; off <<= 1) m = fmaxf(m, __shfl_xor(m, off, 16));
        float e = __expf(s - m);
        float sum = e;
        #pragma unroll
        for (int off = 1; off < 16; off <<= 1) sum += __shfl_xor(sum, off, 16);
        probs[wv][qi][kj] = e / sum;
    }

    __syncthreads();

    __hip_bfloat16* ab = (__hip_bfloat16*)ovbuf;
    #pragma unroll
    for (int qi = 0; qi < 12; ++qi) {
        const f32x4* pr = (const f32x4*)&probs[wv][qi][0];
        f32x4 p0 = pr[0], p1 = pr[1], p2 = pr[2];
        float acc = 0.f;
        #pragma unroll
        for (int j = 0; j < 4; ++j) acc += p0[j] * vv[j] + p1[j] * vv[j + 4] + p2[j] * vv[j + 8];
        ab[qi * 520 + h * 64 + d] = __float2bfloat16(acc);
    }
    {
        unsigned* az = (unsigned*)(ovbuf + 12 * 520);
        for (int i = tid; i < 1040; i += 512) az[i] = 0u;
    }
    __syncthreads();

    {
        const short* Ws = (const short*)Wb;
        const short* As = ovbuf;
        f32x4 acc[4] = {};
        const int n_lane = wv * 64 + rA;
        #pragma unroll 4
        for (int kk = 0; kk < 16; ++kk) {
            int k0 = kk * 32 + g * 8;
            bf16x8 af = *(const bf16x8*)(As + rA * 520 + k0);
            #pragma unroll
            for (int i = 0; i < 4; ++i) {
                bf16x8 bfg = *(const bf16x8*)(Ws + (size_t)(n_lane + i * 16) * NDM + k0);
                acc[i] = __builtin_amdgcn_mfma_f32_16x16x32_bf16(af, bfg, acc[i], 0, 0, 0);
            }
        }
        float* outb = gout + (size_t)b * (NS * NDM);
        const int m0 = g * 4;
        #pragma unroll
        for (int i = 0; i < 4; ++i) {
            int n = wv * 64 + i * 16 + rA;
            float bias = gbo[n];
            #pragma unroll
            for (int r = 0; r < 4; ++r) {
                int m = m0 + r;
                if (m < 12) outb[m * NDM + n] = acc[i][r] + bias;
            }
        }
    }
}

extern "C" void kernel_launch(void* const* d_in, const int* in_sizes, int n_in,
                              void* d_out, int out_size, void* d_ws, size_t ws_size,
                              hipStream_t stream) {
    const float* q    = (const float*)d_in[0];
    const float* k    = (const float*)d_in[1];
    const float* v    = (const float*)d_in[2];
    const int*   mask = (const int*)d_in[3];
    const float* cw   = (const float*)d_in[4];
    const float* cb   = (const float*)d_in[5];
    const float* W    = (const float*)d_in[6];
    const float* bo   = (const float*)d_in[7];

    const size_t TEN = (size_t)NB * NH * NS * NDK * sizeof(short);
    const size_t REQ = 3 * TEN + (size_t)NDM * NDM * sizeof(short);

    if (ws_size >= REQ) {
        short* vc = (short*)d_ws;
        short* qc = vc + TEN / sizeof(short);
        short* kc = qc + TEN / sizeof(short);
        __hip_bfloat16* Wb = (__hip_bfloat16*)(kc + TEN / sizeof(short));

        hipLaunchKernelGGL(wcvt_kernel, dim3(512), dim3(512), 0, stream, W, Wb);
        hipLaunchKernelGGL(conv3_kernel, dim3(NB * 512 / 256, 3), dim3(256), 0, stream,
                           q, k, v, cw, cb, qc, kc, vc);
        hipLaunchKernelGGL(attn2_kernel, dim3(NB / 4), dim3(512), 0, stream,
                           qc, kc, vc, mask, Wb, bo, (float*)d_out);
    } else {
        __hip_bfloat16* Wb = (__hip_bfloat16*)d_ws;
        hipLaunchKernelGGL(wcvt_kernel, dim3(512), dim3(512), 0, stream, W, Wb);
        hipLaunchKernelGGL(mha_fused4_kernel, dim3(NB), dim3(512), 0, stream,
                           q, k, v, mask, cw, cb, Wb, bo, (float*)d_out);
    }
}